// Round 16
// baseline (711.991 us; speedup 1.0000x reference)
//
#include <hip/hip_runtime.h>

#define N_NODES 50000
#define N_EDGES 800000
#define PDIM 3
#define FDIM 64
#define MDIM 32
#define NLAYERS 2
#define EINDIM 129
#define H1 258
#define CH 128
#define NH 128
#define XDIM 67
#define H1T 288
#define HSTR2 40        // hLds col stride (bf16): 80B = 5 quanta (odd -> conflict-free b128)
#define W1T_K 136
#define MLSTR 40
#define NINS 104
#define NH1S 136
#define NW2K 128

typedef __attribute__((ext_vector_type(8))) short short8;
typedef __attribute__((ext_vector_type(4))) float f32x4;

#define LOG2E 1.4426950408889634f

__device__ __forceinline__ float fsilu(float x) {
  float e = __builtin_amdgcn_exp2f(-x * LOG2E);
  return x * __builtin_amdgcn_rcpf(1.0f + e);
}

__device__ __forceinline__ float ftanh(float x) {
  float xc = fminf(fmaxf(x, -15.0f), 15.0f);
  float E = __builtin_amdgcn_exp2f(2.0f * LOG2E * xc);
  return (E - 1.0f) * __builtin_amdgcn_rcpf(E + 1.0f);
}

__device__ __forceinline__ unsigned short f2bf(float f) {
  union { float f; unsigned u; } v; v.f = f;
  unsigned r = v.u + 0x7FFF + ((v.u >> 16) & 1);  // RNE
  return (unsigned short)(r >> 16);
}

__device__ __forceinline__ unsigned cvt_pk(float lo, float hi) {
  unsigned r;
  asm("v_cvt_pk_bf16_f32 %0, %1, %2" : "=v"(r) : "v"(lo), "v"(hi));
  return r;
}

// bijective XCD-chunk swizzle (m204)
__device__ __forceinline__ int xcd_swz(int bid, int nwg) {
  const int nx = 8;
  int q = nwg / nx, r = nwg % nx;
  int xcd = bid % nx, idx = bid / nx;
  return (xcd < r) ? xcd * (q + 1) + idx : r * (q + 1) + (xcd - r) * q + idx;
}

#define COUNT_BLOCKS 3125   // 800000/256
#define PREP_TOTAL (NLAYERS * (H1T * W1T_K + MDIM * H1T + CH * MDIM + 2 * H1T \
                               + NH * NINS + FDIM * NW2K))
#define PREP_BLOCKS ((PREP_TOTAL + 255) / 256)
#define CONV_BLOCKS ((N_NODES * 8 + 255) / 256)

// fused setup: count histogram + weight prep + X bf16 conversion
__global__ void setup_kernel(const int* __restrict__ ei, int* __restrict__ cnt,
                             const float* __restrict__ eW1, const float* __restrict__ eW2,
                             const float* __restrict__ cW1, const float* __restrict__ eb1,
                             const float* __restrict__ nW1, const float* __restrict__ nW2,
                             unsigned short* __restrict__ w1t, unsigned short* __restrict__ w2t,
                             unsigned short* __restrict__ cw1t,
                             unsigned short* __restrict__ nw1t, unsigned short* __restrict__ nw2t,
                             float* __restrict__ b1p, float* __restrict__ wrp,
                             const float* __restrict__ X, unsigned short* __restrict__ Xb) {
  const int bid = blockIdx.x;
  const int tid = threadIdx.x;
  if (bid < COUNT_BLOCKS) {
    int e = bid * 256 + tid;
    if (e < N_EDGES) atomicAdd(&cnt[ei[N_EDGES + e]], 1);
    return;
  }
  if (bid < COUNT_BLOCKS + PREP_BLOCKS) {
    int idx = (bid - COUNT_BLOCKS) * 256 + tid;
    const int n1 = NLAYERS * H1T * W1T_K;
    const int n2 = NLAYERS * MDIM * H1T;
    const int n3 = NLAYERS * CH * MDIM;
    const int n4 = NLAYERS * H1T;
    const int n5 = NLAYERS * NH * NINS;
    const int n6 = NLAYERS * FDIM * NW2K;
    if (idx < n1) {
      int k = idx % W1T_K;
      int rest = idx / W1T_K;
      int j = rest % H1T;
      int l = rest / H1T;
      float v = (k < 128 && j < H1) ? eW1[(l * EINDIM + k) * H1 + j] : 0.0f;
      w1t[idx] = f2bf(v);
    } else if (idx < n1 + n2) {
      int t = idx - n1;
      int k = t % H1T;
      int rest = t / H1T;
      int n = rest % MDIM;
      int l = rest / MDIM;
      float v = (k < H1) ? eW2[(l * H1 + k) * MDIM + n] : 0.0f;
      w2t[t] = f2bf(v);
    } else if (idx < n1 + n2 + n3) {
      int t = idx - n1 - n2;
      int k = t % MDIM;
      int rest = t / MDIM;
      int n = rest % CH;
      int l = rest / CH;
      cw1t[t] = f2bf(cW1[(l * MDIM + k) * CH + n]);
    } else if (idx < n1 + n2 + n3 + n4) {
      int t = idx - n1 - n2 - n3;
      int j = t % H1T;
      int l = t / H1T;
      b1p[t] = (j < H1) ? eb1[l * H1 + j] : 0.0f;
    } else if (idx < n1 + n2 + n3 + 2 * n4) {
      int t = idx - n1 - n2 - n3 - n4;
      int j = t % H1T;
      int l = t / H1T;
      wrp[t] = (j < H1) ? eW1[((size_t)l * EINDIM + 128) * H1 + j] : 0.0f;
    } else if (idx < n1 + n2 + n3 + 2 * n4 + n5) {
      int t = idx - n1 - n2 - n3 - 2 * n4;
      int k = t % NINS;
      int rest = t / NINS;
      int j = rest % NH;
      int l = rest / NH;
      float v = (k < FDIM + MDIM) ? nW1[(l * (FDIM + MDIM) + k) * NH + j] : 0.0f;
      nw1t[t] = f2bf(v);
    } else if (idx < n1 + n2 + n3 + 2 * n4 + n5 + n6) {
      int t = idx - n1 - n2 - n3 - 2 * n4 - n5;
      int k = t % NW2K;
      int rest = t / NW2K;
      int j = rest % FDIM;
      int l = rest / FDIM;
      nw2t[t] = f2bf(nW2[(l * NH + k) * FDIM + j]);
    }
    return;
  }
  {
    int idx = (bid - COUNT_BLOCKS - PREP_BLOCKS) * 256 + tid;
    if (idx >= N_NODES * 8) return;
    int n = idx >> 3, c = idx & 7;
    const float* src = X + n * XDIM + PDIM + c * 8;
    short8 v;
    #pragma unroll
    for (int i = 0; i < 8; ++i) v[i] = (short)f2bf(src[i]);
    *(short8*)&Xb[n * 64 + c * 8] = v;
  }
}

__global__ __launch_bounds__(1024)
void scan_kernel(const int* __restrict__ cnt, int* __restrict__ csr, int* __restrict__ cursor) {
  __shared__ int partial[1024];
  const int tid = threadIdx.x;
  const int CHUNK = 49;
  int base = tid * CHUNK;
  int s = 0;
  for (int i = 0; i < CHUNK; ++i) {
    int idx = base + i;
    if (idx < N_NODES) s += cnt[idx];
  }
  partial[tid] = s;
  __syncthreads();
  for (int off = 1; off < 1024; off <<= 1) {
    int v = (tid >= off) ? partial[tid - off] : 0;
    __syncthreads();
    partial[tid] += v;
    __syncthreads();
  }
  int run = partial[tid] - s;
  for (int i = 0; i < CHUNK; ++i) {
    int idx = base + i;
    if (idx < N_NODES) {
      csr[idx] = run;
      cursor[idx] = run;
      run += cnt[idx];
    }
  }
  if (tid == 1023) csr[N_NODES] = run;
}

__global__ void rank_kernel(const int* __restrict__ ei, int* __restrict__ cursor,
                            int* __restrict__ srcS, int* __restrict__ dstS) {
  int e = blockIdx.x * 256 + threadIdx.x;
  if (e < N_EDGES) {
    int s = ei[e];
    int d = ei[N_EDGES + e];
    int p = atomicAdd(&cursor[d], 1);
    srcS[p] = s;
    dstS[p] = d;
  }
}

// Edge kernel v6: ONE WAVE per block (32 edges). The kernel has zero cross-wave
// traffic, so 1-wave blocks cut LDS/block to 5.1KB (31 blocks/CU possible) and
// decouple occupancy from the 256-thread waves-per-eu budget weirdness.
// (64,5): register budget 512/5 ~= 102 >> 64 natural -> no spill.
__global__ __launch_bounds__(64, 5)
void edge_mfma_kernel(const float* __restrict__ X,
                      const unsigned short* __restrict__ Xb,
                      const int* __restrict__ srcS, const int* __restrict__ dstS,
                      const unsigned short* __restrict__ w1t,
                      const float* __restrict__ b1p, const float* __restrict__ wrp,
                      const unsigned short* __restrict__ w2t, const float* __restrict__ eb2,
                      const unsigned short* __restrict__ cw1t, const float* __restrict__ cb1,
                      const float* __restrict__ cW2, const float* __restrict__ cb2,
                      const float* __restrict__ cscale,
                      unsigned short* __restrict__ ms, float* __restrict__ mh4,
                      int layer)
{
  __shared__ unsigned short hLds[32 * HSTR2];  // 2560 B
  __shared__ unsigned short ml[32 * MLSTR];    // 2560 B

  const int lane = threadIdx.x & 63;
  const int ln15 = lane & 15;
  const int kg = lane >> 4;
  const int e0 = xcd_swz(blockIdx.x, gridDim.x) * 32;

  const int eA = e0 + ln15;
  const int eB = e0 + 16 + ln15;
  const int sA = srcS[eA], dA = dstS[eA];
  const int sB = srcS[eB], dB = dstS[eB];
  float rxA = X[sA * XDIM + 0] - X[dA * XDIM + 0];
  float ryA = X[sA * XDIM + 1] - X[dA * XDIM + 1];
  float rzA = X[sA * XDIM + 2] - X[dA * XDIM + 2];
  float rxB = X[sB * XDIM + 0] - X[dB * XDIM + 0];
  float ryB = X[sB * XDIM + 1] - X[dB * XDIM + 1];
  float rzB = X[sB * XDIM + 2] - X[dB * XDIM + 2];
  const float distA = rxA * rxA + ryA * ryA + rzA * rzA;
  const float distB = rxB * rxB + ryB * ryB + rzB * rzB;

  short8 einB[2][4];
  #pragma unroll
  for (int ks = 0; ks < 4; ++ks) {
    int nA = (ks < 2) ? dA : sA;
    int nB = (ks < 2) ? dB : sB;
    einB[0][ks] = *(const short8*)&Xb[nA * 64 + (ks & 1) * 32 + kg * 8];
    einB[1][ks] = *(const short8*)&Xb[nB * 64 + (ks & 1) * 32 + kg * 8];
  }

  const unsigned short* W1T = w1t + layer * H1T * W1T_K;
  const float* B1P = b1p + layer * H1T;
  const float* WRP = wrp + layer * H1T;
  const unsigned short* W2T = w2t + layer * MDIM * H1T;
  const float* B2 = eb2 + layer * MDIM;

  float b20 = B2[ln15], b21 = B2[16 + ln15];
  f32x4 mac[2][2];
  #pragma unroll
  for (int et = 0; et < 2; ++et) {
    mac[et][0] = (f32x4){b20, b20, b20, b20};
    mac[et][1] = (f32x4){b21, b21, b21, b21};
  }

  // ---- 9 chunks of 32 h-cols; B then C per chunk; all LDS wave-local ----
  #pragma unroll 1
  for (int chunk = 0; chunk < 9; ++chunk) {
    #pragma unroll
    for (int jl = 0; jl < 2; ++jl) {
      const int jt = chunk * 2 + jl;
      f32x4 b4 = *(const f32x4*)&B1P[jt * 16 + kg * 4];
      f32x4 w4 = *(const f32x4*)&WRP[jt * 16 + kg * 4];
      short8 a[4];
      #pragma unroll
      for (int ks = 0; ks < 4; ++ks)
        a[ks] = *(const short8*)&W1T[(jt * 16 + ln15) * W1T_K + ks * 32 + kg * 8];
      #pragma unroll
      for (int et = 0; et < 2; ++et) {
        const float dv = et ? distB : distA;
        f32x4 acc;
        #pragma unroll
        for (int r = 0; r < 4; ++r) acc[r] = fmaf(dv, w4[r], b4[r]);
        #pragma unroll
        for (int ks = 0; ks < 4; ++ks)
          acc = __builtin_amdgcn_mfma_f32_16x16x32_bf16(a[ks], einB[et][ks], acc, 0, 0, 0);
        uint2 uu;
        uu.x = cvt_pk(fsilu(acc[0]), fsilu(acc[1]));
        uu.y = cvt_pk(fsilu(acc[2]), fsilu(acc[3]));
        *(uint2*)&hLds[(et * 16 + ln15) * HSTR2 + jl * 16 + kg * 4] = uu;
      }
    }
    // phase C partial: this chunk's 32 k values
    {
      const int kglob = chunk * 32;
      short8 w0 = *(const short8*)&W2T[ln15 * H1T + kglob + kg * 8];
      short8 w1 = *(const short8*)&W2T[(16 + ln15) * H1T + kglob + kg * 8];
      #pragma unroll
      for (int et = 0; et < 2; ++et) {
        short8 ah = *(const short8*)&hLds[(et * 16 + ln15) * HSTR2 + kg * 8];
        mac[et][0] = __builtin_amdgcn_mfma_f32_16x16x32_bf16(ah, w0, mac[et][0], 0, 0, 0);
        mac[et][1] = __builtin_amdgcn_mfma_f32_16x16x32_bf16(ah, w1, mac[et][1], 0, 0, 0);
      }
    }
  }

  #pragma unroll
  for (int et = 0; et < 2; ++et) {
    #pragma unroll
    for (int r = 0; r < 4; ++r) {
      int eg = et * 16 + kg * 4 + r;
      ml[eg * MLSTR + ln15] = f2bf(fsilu(mac[et][0][r]));
      ml[eg * MLSTR + 16 + ln15] = f2bf(fsilu(mac[et][1][r]));
    }
  }

  const unsigned short* CW1T = cw1t + layer * CH * MDIM;
  const float* CB1 = cb1 + layer * CH;
  const float* CW2v = cW2 + layer * CH;
  short8 amA = *(const short8*)&ml[ln15 * MLSTR + kg * 8];
  short8 amB = *(const short8*)&ml[(16 + ln15) * MLSTR + kg * 8];
  float psA[4] = {0.f, 0.f, 0.f, 0.f};
  float psB[4] = {0.f, 0.f, 0.f, 0.f};
  #pragma unroll
  for (int nt = 0; nt < 8; ++nt) {
    float cb = CB1[nt * 16 + ln15];
    float w2v = CW2v[nt * 16 + ln15];
    short8 bc = *(const short8*)&CW1T[(nt * 16 + ln15) * MDIM + kg * 8];
    f32x4 cA = {cb, cb, cb, cb};
    f32x4 cB = {cb, cb, cb, cb};
    cA = __builtin_amdgcn_mfma_f32_16x16x32_bf16(amA, bc, cA, 0, 0, 0);
    cB = __builtin_amdgcn_mfma_f32_16x16x32_bf16(amB, bc, cB, 0, 0, 0);
    #pragma unroll
    for (int r = 0; r < 4; ++r) {
      psA[r] += fsilu(cA[r]) * w2v;
      psB[r] += fsilu(cB[r]) * w2v;
    }
  }
  #pragma unroll
  for (int off = 1; off < 16; off <<= 1) {
    #pragma unroll
    for (int r = 0; r < 4; ++r) {
      psA[r] += __shfl_xor(psA[r], off, 64);
      psB[r] += __shfl_xor(psB[r], off, 64);
    }
  }
  float cwvA = 0.0f, cwvB = 0.0f;
  #pragma unroll
  for (int r = 0; r < 4; ++r) {
    float tA = __shfl(psA[r], ((lane & 15) >> 2) * 16, 64);
    float tB = __shfl(psB[r], ((lane & 15) >> 2) * 16, 64);
    if ((lane & 3) == r) { cwvA = tA; cwvB = tB; }
  }

  #pragma unroll
  for (int it = 0; it < 2; ++it) {
    int idx = lane + it * 64;
    int el = idx >> 2, seg = idx & 3;
    short8 v = *(const short8*)&ml[el * MLSTR + seg * 8];
    *(short8*)&ms[(size_t)(e0 + el) * MDIM + seg * 8] = v;
  }
  if (lane < 32) {
    const int hi = lane >> 4;
    float cwv = hi ? cwvB : cwvA;
    float dv = hi ? distB : distA;
    float rx = hi ? rxB : rxA, ry = hi ? ryB : ryA, rz = hi ? rzB : rzA;
    float cw = ftanh(cwv + cb2[layer]);
    float fac = cw * cscale[layer] / fmaxf(sqrtf(dv), 1e-8f);
    *(float4*)&mh4[(size_t)(e0 + lane) * 4] = make_float4(fac * rx, fac * ry, fac * rz, 0.0f);
  }
}

// ---- MFMA node kernel v3 (frozen from R14/R15) ----
__global__ __launch_bounds__(256, 5)
void node_mfma_kernel(const float* __restrict__ Xin,
                      const unsigned short* __restrict__ XbIn,
                      const unsigned short* __restrict__ ms,
                      const float* __restrict__ mh4,
                      const int* __restrict__ csr,
                      const unsigned short* __restrict__ nw1t, const float* __restrict__ nb1,
                      const unsigned short* __restrict__ nw2t, const float* __restrict__ nb2,
                      float* __restrict__ Xout, unsigned short* __restrict__ XbOut,
                      int writeXb, int layer)
{
  __shared__ unsigned short ninLds[64 * NINS];  // 13312 B
  __shared__ unsigned short h1Lds[64 * NH1S];   // 17408 B, reused as f32 out[64][68]
  __shared__ int csrLds[65];
  float* outLds = (float*)h1Lds;

  const int tid = threadIdx.x;
  const int lane = tid & 63;
  const int wid = tid >> 6;
  const int ln15 = lane & 15;
  const int kg = lane >> 4;
  const int n0 = xcd_swz(blockIdx.x, gridDim.x) * 64;

  if (tid < 65) {
    int nn = n0 + tid;
    csrLds[tid] = (nn <= N_NODES) ? csr[nn] : 0;
  }
  #pragma unroll
  for (int it = 0; it < 2; ++it) {
    int idx = tid + it * 256;
    int nl = idx >> 3, c = idx & 7;
    int n = n0 + nl;
    uint4 v = make_uint4(0, 0, 0, 0);
    if (n < N_NODES) v = *(const uint4*)&XbIn[n * 64 + c * 8];
    *(uint4*)&ninLds[nl * NINS + c * 8] = v;
  }
  __syncthreads();

  // gather m_i + mhat: 8 threads/node, 2 passes
  #pragma unroll 1
  for (int pass = 0; pass < 2; ++pass) {
    const int nl = (tid >> 3) + pass * 32;
    const int sub = tid & 7;
    const int colq = sub & 3;
    const int rhalf = sub >> 2;
    const int n = n0 + nl;
    int off = csrLds[nl], end = csrLds[nl + 1];
    if (n >= N_NODES) { off = 0; end = 0; }
    float s0 = 0, s1 = 0, s2 = 0, s3 = 0, s4 = 0, s5 = 0, s6 = 0, s7 = 0;
    for (int r = off + rhalf; r < end; r += 2) {
      uint4 q = *(const uint4*)&ms[(size_t)r * MDIM + colq * 8];
      union { unsigned u; float f; } t;
      t.u = q.x << 16;         s0 += t.f;
      t.u = q.x & 0xFFFF0000u; s1 += t.f;
      t.u = q.y << 16;         s2 += t.f;
      t.u = q.y & 0xFFFF0000u; s3 += t.f;
      t.u = q.z << 16;         s4 += t.f;
      t.u = q.z & 0xFFFF0000u; s5 += t.f;
      t.u = q.w << 16;         s6 += t.f;
      t.u = q.w & 0xFFFF0000u; s7 += t.f;
    }
    s0 += __shfl_xor(s0, 4, 64);
    s1 += __shfl_xor(s1, 4, 64);
    s2 += __shfl_xor(s2, 4, 64);
    s3 += __shfl_xor(s3, 4, 64);
    s4 += __shfl_xor(s4, 4, 64);
    s5 += __shfl_xor(s5, 4, 64);
    s6 += __shfl_xor(s6, 4, 64);
    s7 += __shfl_xor(s7, 4, 64);
    if (rhalf == 0) {
      uint4 mo;
      mo.x = cvt_pk(s0, s1);
      mo.y = cvt_pk(s2, s3);
      mo.z = cvt_pk(s4, s5);
      mo.w = cvt_pk(s6, s7);
      *(uint4*)&ninLds[nl * NINS + FDIM + colq * 8] = mo;
    }
    float mx = 0, my = 0, mz = 0;
    for (int r = off + sub; r < end; r += 8) {
      float4 q = *(const float4*)&mh4[(size_t)r * 4];
      mx += q.x; my += q.y; mz += q.z;
    }
    mx += __shfl_xor(mx, 1, 64); mx += __shfl_xor(mx, 2, 64); mx += __shfl_xor(mx, 4, 64);
    my += __shfl_xor(my, 1, 64); my += __shfl_xor(my, 2, 64); my += __shfl_xor(my, 4, 64);
    mz += __shfl_xor(mz, 1, 64); mz += __shfl_xor(mz, 2, 64); mz += __shfl_xor(mz, 4, 64);
    if (sub == 0 && n < N_NODES) {
      Xout[n * XDIM + 0] = Xin[n * XDIM + 0] + mx;
      Xout[n * XDIM + 1] = Xin[n * XDIM + 1] + my;
      Xout[n * XDIM + 2] = Xin[n * XDIM + 2] + mz;
    }
  }
  __syncthreads();

  // M1: h1T = silu(nW1T . n_inT + nb1)
  const unsigned short* W1 = nw1t + layer * NH * NINS;
  const float* B1 = nb1 + layer * NH;
  for (int jt = wid; jt < 8; jt += 4) {
    f32x4 b4 = *(const f32x4*)&B1[jt * 16 + kg * 4];
    short8 a[3];
    #pragma unroll
    for (int ks = 0; ks < 3; ++ks)
      a[ks] = *(const short8*)&W1[(jt * 16 + ln15) * NINS + ks * 32 + kg * 8];
    #pragma unroll
    for (int et = 0; et < 4; ++et) {
      f32x4 acc = b4;
      #pragma unroll
      for (int ks = 0; ks < 3; ++ks) {
        short8 b = *(const short8*)&ninLds[(et * 16 + ln15) * NINS + ks * 32 + kg * 8];
        acc = __builtin_amdgcn_mfma_f32_16x16x32_bf16(a[ks], b, acc, 0, 0, 0);
      }
      uint2 uu;
      uu.x = cvt_pk(fsilu(acc[0]), fsilu(acc[1]));
      uu.y = cvt_pk(fsilu(acc[2]), fsilu(acc[3]));
      *(uint2*)&h1Lds[(et * 16 + ln15) * NH1S + jt * 16 + kg * 4] = uu;
    }
  }
  __syncthreads();

  // M2: outT = nW2T . h1T + nb2
  const unsigned short* W2 = nw2t + layer * FDIM * NW2K;
  const float* B2 = nb2 + layer * FDIM;
  f32x4 oacc[4];
  {
    int jt = wid;
    f32x4 b4 = *(const f32x4*)&B2[jt * 16 + kg * 4];
    short8 a[4];
    #pragma unroll
    for (int ks = 0; ks < 4; ++ks)
      a[ks] = *(const short8*)&W2[(jt * 16 + ln15) * NW2K + ks * 32 + kg * 8];
    #pragma unroll
    for (int et = 0; et < 4; ++et) {
      f32x4 acc = b4;
      #pragma unroll
      for (int ks = 0; ks < 4; ++ks) {
        short8 b = *(const short8*)&h1Lds[(et * 16 + ln15) * NH1S + ks * 32 + kg * 8];
        acc = __builtin_amdgcn_mfma_f32_16x16x32_bf16(a[ks], b, acc, 0, 0, 0);
      }
      oacc[et] = acc;
    }
  }
  __syncthreads();
  {
    int jt = wid;
    #pragma unroll
    for (int et = 0; et < 4; ++et)
      *(f32x4*)&outLds[(et * 16 + ln15) * 68 + jt * 16 + kg * 4] = oacc[et];
  }
  __syncthreads();

  #pragma unroll
  for (int it = 0; it < 16; ++it) {
    int idx = tid + it * 256;
    int nl = idx >> 6, c = idx & 63;
    int n = n0 + nl;
    if (n < N_NODES) {
      float v = Xin[n * XDIM + PDIM + c] + outLds[nl * 68 + c];
      Xout[n * XDIM + PDIM + c] = v;
      if (writeXb) XbOut[n * 64 + c] = f2bf(v);
    }
  }
}

extern "C" void kernel_launch(void* const* d_in, const int* in_sizes, int n_in,
                              void* d_out, int out_size, void* d_ws, size_t ws_size,
                              hipStream_t stream) {
  const float* x      = (const float*)d_in[0];
  const int*   ei     = (const int*)d_in[1];
  const float* eW1    = (const float*)d_in[2];
  const float* eb1    = (const float*)d_in[3];
  const float* eW2    = (const float*)d_in[4];
  const float* eb2    = (const float*)d_in[5];
  const float* cW1    = (const float*)d_in[6];
  const float* cb1    = (const float*)d_in[7];
  const float* cW2    = (const float*)d_in[8];
  const float* cb2    = (const float*)d_in[9];
  const float* nW1    = (const float*)d_in[10];
  const float* nb1    = (const float*)d_in[11];
  const float* nW2    = (const float*)d_in[12];
  const float* nb2    = (const float*)d_in[13];
  const float* cscale = (const float*)d_in[14];

  float* ws     = (float*)d_ws;
  float* X1     = ws;                                   // N*67 f32
  float* mh4    = X1 + N_NODES * XDIM;                  // E*4 f32
  int*   csr    = (int*)(mh4 + (size_t)N_EDGES * 4);    // N+4
  int*   cursor = csr + N_NODES + 4;                    // N
  int*   cnt    = cursor + N_NODES;                     // N
  int*   srcS   = cnt + N_NODES;                        // E
  int*   dstS   = srcS + N_EDGES;                       // E
  unsigned short* w1t  = (unsigned short*)(dstS + N_EDGES);
  unsigned short* w2t  = w1t + NLAYERS * H1T * W1T_K;
  unsigned short* cw1t = w2t + NLAYERS * MDIM * H1T;
  unsigned short* nw1t = cw1t + NLAYERS * CH * MDIM;
  unsigned short* nw2t = nw1t + NLAYERS * NH * NINS;
  float* b1p = (float*)(nw2t + NLAYERS * FDIM * NW2K);
  float* wrp = b1p + NLAYERS * H1T;
  unsigned short* Xb = (unsigned short*)(wrp + NLAYERS * H1T);  // N*64 bf16
  unsigned short* ms = Xb + (size_t)N_NODES * 64;               // E*32 bf16

  hipMemsetAsync(cnt, 0, N_NODES * sizeof(int), stream);
  setup_kernel<<<COUNT_BLOCKS + PREP_BLOCKS + CONV_BLOCKS, 256, 0, stream>>>(
      ei, cnt, eW1, eW2, cW1, eb1, nW1, nW2,
      w1t, w2t, cw1t, nw1t, nw2t, b1p, wrp, x, Xb);
  scan_kernel<<<1, 1024, 0, stream>>>(cnt, csr, cursor);
  rank_kernel<<<(N_EDGES + 255) / 256, 256, 0, stream>>>(ei, cursor, srcS, dstS);

  const int nodeBlocks = (N_NODES + 63) / 64;
  for (int l = 0; l < NLAYERS; ++l) {
    const float* Xin = (l == 0) ? x : X1;
    float* Xout = (l == 0) ? X1 : (float*)d_out;
    edge_mfma_kernel<<<N_EDGES / 32, 64, 0, stream>>>(
        Xin, Xb, srcS, dstS, w1t, b1p, wrp, w2t, eb2, cw1t, cb1, cW2, cb2, cscale,
        ms, mh4, l);
    node_mfma_kernel<<<nodeBlocks, 256, 0, stream>>>(
        Xin, Xb, ms, mh4, csr, nw1t, nb1, nw2t, nb2, Xout, Xb, (l == 0) ? 1 : 0, l);
  }
}

// Round 17
// 659.992 us; speedup vs baseline: 1.0788x; 1.0788x over previous
//
#include <hip/hip_runtime.h>

#define N_NODES 50000
#define N_EDGES 800000
#define PDIM 3
#define FDIM 64
#define MDIM 32
#define NLAYERS 2
#define EINDIM 129
#define H1 258
#define CH 128
#define NH 128
#define XDIM 67
#define H1T 288
#define HSTR2 40        // hLds col stride (bf16): 80B = 5 quanta (odd -> conflict-free b128)
#define W1T_K 136
#define MLSTR 40
#define NINS 104
#define NH1S 136
#define NW2K 128

typedef __attribute__((ext_vector_type(8))) short short8;
typedef __attribute__((ext_vector_type(4))) float f32x4;

#define LOG2E 1.4426950408889634f

__device__ __forceinline__ float fsilu(float x) {
  float e = __builtin_amdgcn_exp2f(-x * LOG2E);
  return x * __builtin_amdgcn_rcpf(1.0f + e);
}

__device__ __forceinline__ float ftanh(float x) {
  float xc = fminf(fmaxf(x, -15.0f), 15.0f);
  float E = __builtin_amdgcn_exp2f(2.0f * LOG2E * xc);
  return (E - 1.0f) * __builtin_amdgcn_rcpf(E + 1.0f);
}

__device__ __forceinline__ unsigned short f2bf(float f) {
  union { float f; unsigned u; } v; v.f = f;
  unsigned r = v.u + 0x7FFF + ((v.u >> 16) & 1);  // RNE
  return (unsigned short)(r >> 16);
}

__device__ __forceinline__ unsigned cvt_pk(float lo, float hi) {
  unsigned r;
  asm("v_cvt_pk_bf16_f32 %0, %1, %2" : "=v"(r) : "v"(lo), "v"(hi));
  return r;
}

// bijective XCD-chunk swizzle (m204)
__device__ __forceinline__ int xcd_swz(int bid, int nwg) {
  const int nx = 8;
  int q = nwg / nx, r = nwg % nx;
  int xcd = bid % nx, idx = bid / nx;
  return (xcd < r) ? xcd * (q + 1) + idx : r * (q + 1) + (xcd - r) * q + idx;
}

#define COUNT_BLOCKS 3125   // 800000/256
#define PREP_TOTAL (NLAYERS * (H1T * W1T_K + MDIM * H1T + CH * MDIM + 2 * H1T \
                               + NH * NINS + FDIM * NW2K))
#define PREP_BLOCKS ((PREP_TOTAL + 255) / 256)
#define CONV_BLOCKS ((N_NODES * 8 + 255) / 256)

// fused setup: count histogram + weight prep + X bf16 conversion
__global__ void setup_kernel(const int* __restrict__ ei, int* __restrict__ cnt,
                             const float* __restrict__ eW1, const float* __restrict__ eW2,
                             const float* __restrict__ cW1, const float* __restrict__ eb1,
                             const float* __restrict__ nW1, const float* __restrict__ nW2,
                             unsigned short* __restrict__ w1t, unsigned short* __restrict__ w2t,
                             unsigned short* __restrict__ cw1t,
                             unsigned short* __restrict__ nw1t, unsigned short* __restrict__ nw2t,
                             float* __restrict__ b1p, float* __restrict__ wrp,
                             const float* __restrict__ X, unsigned short* __restrict__ Xb) {
  const int bid = blockIdx.x;
  const int tid = threadIdx.x;
  if (bid < COUNT_BLOCKS) {
    int e = bid * 256 + tid;
    if (e < N_EDGES) atomicAdd(&cnt[ei[N_EDGES + e]], 1);
    return;
  }
  if (bid < COUNT_BLOCKS + PREP_BLOCKS) {
    int idx = (bid - COUNT_BLOCKS) * 256 + tid;
    const int n1 = NLAYERS * H1T * W1T_K;
    const int n2 = NLAYERS * MDIM * H1T;
    const int n3 = NLAYERS * CH * MDIM;
    const int n4 = NLAYERS * H1T;
    const int n5 = NLAYERS * NH * NINS;
    const int n6 = NLAYERS * FDIM * NW2K;
    if (idx < n1) {
      int k = idx % W1T_K;
      int rest = idx / W1T_K;
      int j = rest % H1T;
      int l = rest / H1T;
      float v = (k < 128 && j < H1) ? eW1[(l * EINDIM + k) * H1 + j] : 0.0f;
      w1t[idx] = f2bf(v);
    } else if (idx < n1 + n2) {
      int t = idx - n1;
      int k = t % H1T;
      int rest = t / H1T;
      int n = rest % MDIM;
      int l = rest / MDIM;
      float v = (k < H1) ? eW2[(l * H1 + k) * MDIM + n] : 0.0f;
      w2t[t] = f2bf(v);
    } else if (idx < n1 + n2 + n3) {
      int t = idx - n1 - n2;
      int k = t % MDIM;
      int rest = t / MDIM;
      int n = rest % CH;
      int l = rest / CH;
      cw1t[t] = f2bf(cW1[(l * MDIM + k) * CH + n]);
    } else if (idx < n1 + n2 + n3 + n4) {
      int t = idx - n1 - n2 - n3;
      int j = t % H1T;
      int l = t / H1T;
      b1p[t] = (j < H1) ? eb1[l * H1 + j] : 0.0f;
    } else if (idx < n1 + n2 + n3 + 2 * n4) {
      int t = idx - n1 - n2 - n3 - n4;
      int j = t % H1T;
      int l = t / H1T;
      wrp[t] = (j < H1) ? eW1[((size_t)l * EINDIM + 128) * H1 + j] : 0.0f;
    } else if (idx < n1 + n2 + n3 + 2 * n4 + n5) {
      int t = idx - n1 - n2 - n3 - 2 * n4;
      int k = t % NINS;
      int rest = t / NINS;
      int j = rest % NH;
      int l = rest / NH;
      float v = (k < FDIM + MDIM) ? nW1[(l * (FDIM + MDIM) + k) * NH + j] : 0.0f;
      nw1t[t] = f2bf(v);
    } else if (idx < n1 + n2 + n3 + 2 * n4 + n5 + n6) {
      int t = idx - n1 - n2 - n3 - 2 * n4 - n5;
      int k = t % NW2K;
      int rest = t / NW2K;
      int j = rest % FDIM;
      int l = rest / FDIM;
      nw2t[t] = f2bf(nW2[(l * NH + k) * FDIM + j]);
    }
    return;
  }
  {
    int idx = (bid - COUNT_BLOCKS - PREP_BLOCKS) * 256 + tid;
    if (idx >= N_NODES * 8) return;
    int n = idx >> 3, c = idx & 7;
    const float* src = X + n * XDIM + PDIM + c * 8;
    short8 v;
    #pragma unroll
    for (int i = 0; i < 8; ++i) v[i] = (short)f2bf(src[i]);
    *(short8*)&Xb[n * 64 + c * 8] = v;
  }
}

__global__ __launch_bounds__(1024)
void scan_kernel(const int* __restrict__ cnt, int* __restrict__ csr, int* __restrict__ cursor) {
  __shared__ int partial[1024];
  const int tid = threadIdx.x;
  const int CHUNK = 49;
  int base = tid * CHUNK;
  int s = 0;
  for (int i = 0; i < CHUNK; ++i) {
    int idx = base + i;
    if (idx < N_NODES) s += cnt[idx];
  }
  partial[tid] = s;
  __syncthreads();
  for (int off = 1; off < 1024; off <<= 1) {
    int v = (tid >= off) ? partial[tid - off] : 0;
    __syncthreads();
    partial[tid] += v;
    __syncthreads();
  }
  int run = partial[tid] - s;
  for (int i = 0; i < CHUNK; ++i) {
    int idx = base + i;
    if (idx < N_NODES) {
      csr[idx] = run;
      cursor[idx] = run;
      run += cnt[idx];
    }
  }
  if (tid == 1023) csr[N_NODES] = run;
}

__global__ void rank_kernel(const int* __restrict__ ei, int* __restrict__ cursor,
                            int* __restrict__ srcS, int* __restrict__ dstS) {
  int e = blockIdx.x * 256 + threadIdx.x;
  if (e < N_EDGES) {
    int s = ei[e];
    int d = ei[N_EDGES + e];
    int p = atomicAdd(&cursor[d], 1);
    srcS[p] = s;
    dstS[p] = d;
  }
}

// Edge kernel (best-known, R15): 9x(2 j-tile B + 1 C) chunks, 20.5KB LDS,
// launch_bounds(256,4) -> 128-VGPR budget, VGPR=64, no spill, 220us.
__global__ __launch_bounds__(256, 4)
void edge_mfma_kernel(const float* __restrict__ X,
                      const unsigned short* __restrict__ Xb,
                      const int* __restrict__ srcS, const int* __restrict__ dstS,
                      const unsigned short* __restrict__ w1t,
                      const float* __restrict__ b1p, const float* __restrict__ wrp,
                      const unsigned short* __restrict__ w2t, const float* __restrict__ eb2,
                      const unsigned short* __restrict__ cw1t, const float* __restrict__ cb1,
                      const float* __restrict__ cW2, const float* __restrict__ cb2,
                      const float* __restrict__ cscale,
                      unsigned short* __restrict__ ms, float* __restrict__ mh4,
                      int layer)
{
  __shared__ unsigned short hLds[128 * HSTR2];  // 10240 B, wave-partitioned rows
  __shared__ unsigned short ml[128 * MLSTR];    // 10240 B

  const int tid = threadIdx.x;
  const int lane = tid & 63;
  const int wid = tid >> 6;
  const int ln15 = lane & 15;
  const int kg = lane >> 4;
  const int e0 = xcd_swz(blockIdx.x, gridDim.x) * 128;
  const int ew0 = e0 + wid * 32;

  const int eA = ew0 + ln15;
  const int eB = ew0 + 16 + ln15;
  const int sA = srcS[eA], dA = dstS[eA];
  const int sB = srcS[eB], dB = dstS[eB];
  float rxA = X[sA * XDIM + 0] - X[dA * XDIM + 0];
  float ryA = X[sA * XDIM + 1] - X[dA * XDIM + 1];
  float rzA = X[sA * XDIM + 2] - X[dA * XDIM + 2];
  float rxB = X[sB * XDIM + 0] - X[dB * XDIM + 0];
  float ryB = X[sB * XDIM + 1] - X[dB * XDIM + 1];
  float rzB = X[sB * XDIM + 2] - X[dB * XDIM + 2];
  const float distA = rxA * rxA + ryA * ryA + rzA * rzA;
  const float distB = rxB * rxB + ryB * ryB + rzB * rzB;

  short8 einB[2][4];
  #pragma unroll
  for (int ks = 0; ks < 4; ++ks) {
    int nA = (ks < 2) ? dA : sA;
    int nB = (ks < 2) ? dB : sB;
    einB[0][ks] = *(const short8*)&Xb[nA * 64 + (ks & 1) * 32 + kg * 8];
    einB[1][ks] = *(const short8*)&Xb[nB * 64 + (ks & 1) * 32 + kg * 8];
  }

  const unsigned short* W1T = w1t + layer * H1T * W1T_K;
  const float* B1P = b1p + layer * H1T;
  const float* WRP = wrp + layer * H1T;
  const unsigned short* W2T = w2t + layer * MDIM * H1T;
  const float* B2 = eb2 + layer * MDIM;

  float b20 = B2[ln15], b21 = B2[16 + ln15];
  f32x4 mac[2][2];
  #pragma unroll
  for (int et = 0; et < 2; ++et) {
    mac[et][0] = (f32x4){b20, b20, b20, b20};
    mac[et][1] = (f32x4){b21, b21, b21, b21};
  }

  // ---- 9 chunks of 32 h-cols; B then C per chunk; all LDS wave-local ----
  #pragma unroll 1
  for (int chunk = 0; chunk < 9; ++chunk) {
    #pragma unroll
    for (int jl = 0; jl < 2; ++jl) {
      const int jt = chunk * 2 + jl;
      f32x4 b4 = *(const f32x4*)&B1P[jt * 16 + kg * 4];
      f32x4 w4 = *(const f32x4*)&WRP[jt * 16 + kg * 4];
      short8 a[4];
      #pragma unroll
      for (int ks = 0; ks < 4; ++ks)
        a[ks] = *(const short8*)&W1T[(jt * 16 + ln15) * W1T_K + ks * 32 + kg * 8];
      #pragma unroll
      for (int et = 0; et < 2; ++et) {
        const float dv = et ? distB : distA;
        f32x4 acc;
        #pragma unroll
        for (int r = 0; r < 4; ++r) acc[r] = fmaf(dv, w4[r], b4[r]);
        #pragma unroll
        for (int ks = 0; ks < 4; ++ks)
          acc = __builtin_amdgcn_mfma_f32_16x16x32_bf16(a[ks], einB[et][ks], acc, 0, 0, 0);
        uint2 uu;
        uu.x = cvt_pk(fsilu(acc[0]), fsilu(acc[1]));
        uu.y = cvt_pk(fsilu(acc[2]), fsilu(acc[3]));
        *(uint2*)&hLds[(wid * 32 + et * 16 + ln15) * HSTR2 + jl * 16 + kg * 4] = uu;
      }
    }
    // phase C partial: this chunk's 32 k values
    {
      const int kglob = chunk * 32;
      short8 w0 = *(const short8*)&W2T[ln15 * H1T + kglob + kg * 8];
      short8 w1 = *(const short8*)&W2T[(16 + ln15) * H1T + kglob + kg * 8];
      #pragma unroll
      for (int et = 0; et < 2; ++et) {
        short8 ah = *(const short8*)&hLds[(wid * 32 + et * 16 + ln15) * HSTR2 + kg * 8];
        mac[et][0] = __builtin_amdgcn_mfma_f32_16x16x32_bf16(ah, w0, mac[et][0], 0, 0, 0);
        mac[et][1] = __builtin_amdgcn_mfma_f32_16x16x32_bf16(ah, w1, mac[et][1], 0, 0, 0);
      }
    }
  }

  #pragma unroll
  for (int et = 0; et < 2; ++et) {
    #pragma unroll
    for (int r = 0; r < 4; ++r) {
      int eg = wid * 32 + et * 16 + kg * 4 + r;
      ml[eg * MLSTR + ln15] = f2bf(fsilu(mac[et][0][r]));
      ml[eg * MLSTR + 16 + ln15] = f2bf(fsilu(mac[et][1][r]));
    }
  }

  const unsigned short* CW1T = cw1t + layer * CH * MDIM;
  const float* CB1 = cb1 + layer * CH;
  const float* CW2v = cW2 + layer * CH;
  short8 amA = *(const short8*)&ml[(wid * 32 + ln15) * MLSTR + kg * 8];
  short8 amB = *(const short8*)&ml[(wid * 32 + 16 + ln15) * MLSTR + kg * 8];
  float psA[4] = {0.f, 0.f, 0.f, 0.f};
  float psB[4] = {0.f, 0.f, 0.f, 0.f};
  #pragma unroll
  for (int nt = 0; nt < 8; ++nt) {
    float cb = CB1[nt * 16 + ln15];
    float w2v = CW2v[nt * 16 + ln15];
    short8 bc = *(const short8*)&CW1T[(nt * 16 + ln15) * MDIM + kg * 8];
    f32x4 cA = {cb, cb, cb, cb};
    f32x4 cB = {cb, cb, cb, cb};
    cA = __builtin_amdgcn_mfma_f32_16x16x32_bf16(amA, bc, cA, 0, 0, 0);
    cB = __builtin_amdgcn_mfma_f32_16x16x32_bf16(amB, bc, cB, 0, 0, 0);
    #pragma unroll
    for (int r = 0; r < 4; ++r) {
      psA[r] += fsilu(cA[r]) * w2v;
      psB[r] += fsilu(cB[r]) * w2v;
    }
  }
  #pragma unroll
  for (int off = 1; off < 16; off <<= 1) {
    #pragma unroll
    for (int r = 0; r < 4; ++r) {
      psA[r] += __shfl_xor(psA[r], off, 64);
      psB[r] += __shfl_xor(psB[r], off, 64);
    }
  }
  float cwvA = 0.0f, cwvB = 0.0f;
  #pragma unroll
  for (int r = 0; r < 4; ++r) {
    float tA = __shfl(psA[r], ((lane & 15) >> 2) * 16, 64);
    float tB = __shfl(psB[r], ((lane & 15) >> 2) * 16, 64);
    if ((lane & 3) == r) { cwvA = tA; cwvB = tB; }
  }

  #pragma unroll
  for (int it = 0; it < 2; ++it) {
    int idx = lane + it * 64;
    int el = idx >> 2, seg = idx & 3;
    short8 v = *(const short8*)&ml[(wid * 32 + el) * MLSTR + seg * 8];
    *(short8*)&ms[(size_t)(ew0 + el) * MDIM + seg * 8] = v;
  }
  if (lane < 32) {
    const int hi = lane >> 4;
    float cwv = hi ? cwvB : cwvA;
    float dv = hi ? distB : distA;
    float rx = hi ? rxB : rxA, ry = hi ? ryB : ryA, rz = hi ? rzB : rzA;
    float cw = ftanh(cwv + cb2[layer]);
    float fac = cw * cscale[layer] / fmaxf(sqrtf(dv), 1e-8f);
    *(float4*)&mh4[(size_t)(ew0 + lane) * 4] = make_float4(fac * rx, fac * ry, fac * rz, 0.0f);
  }
}

// ---- MFMA node kernel v3 (best-known) ----
__global__ __launch_bounds__(256, 5)
void node_mfma_kernel(const float* __restrict__ Xin,
                      const unsigned short* __restrict__ XbIn,
                      const unsigned short* __restrict__ ms,
                      const float* __restrict__ mh4,
                      const int* __restrict__ csr,
                      const unsigned short* __restrict__ nw1t, const float* __restrict__ nb1,
                      const unsigned short* __restrict__ nw2t, const float* __restrict__ nb2,
                      float* __restrict__ Xout, unsigned short* __restrict__ XbOut,
                      int writeXb, int layer)
{
  __shared__ unsigned short ninLds[64 * NINS];  // 13312 B
  __shared__ unsigned short h1Lds[64 * NH1S];   // 17408 B, reused as f32 out[64][68]
  __shared__ int csrLds[65];
  float* outLds = (float*)h1Lds;

  const int tid = threadIdx.x;
  const int lane = tid & 63;
  const int wid = tid >> 6;
  const int ln15 = lane & 15;
  const int kg = lane >> 4;
  const int n0 = xcd_swz(blockIdx.x, gridDim.x) * 64;

  if (tid < 65) {
    int nn = n0 + tid;
    csrLds[tid] = (nn <= N_NODES) ? csr[nn] : 0;
  }
  #pragma unroll
  for (int it = 0; it < 2; ++it) {
    int idx = tid + it * 256;
    int nl = idx >> 3, c = idx & 7;
    int n = n0 + nl;
    uint4 v = make_uint4(0, 0, 0, 0);
    if (n < N_NODES) v = *(const uint4*)&XbIn[n * 64 + c * 8];
    *(uint4*)&ninLds[nl * NINS + c * 8] = v;
  }
  __syncthreads();

  // gather m_i + mhat: 8 threads/node, 2 passes
  #pragma unroll 1
  for (int pass = 0; pass < 2; ++pass) {
    const int nl = (tid >> 3) + pass * 32;
    const int sub = tid & 7;
    const int colq = sub & 3;
    const int rhalf = sub >> 2;
    const int n = n0 + nl;
    int off = csrLds[nl], end = csrLds[nl + 1];
    if (n >= N_NODES) { off = 0; end = 0; }
    float s0 = 0, s1 = 0, s2 = 0, s3 = 0, s4 = 0, s5 = 0, s6 = 0, s7 = 0;
    for (int r = off + rhalf; r < end; r += 2) {
      uint4 q = *(const uint4*)&ms[(size_t)r * MDIM + colq * 8];
      union { unsigned u; float f; } t;
      t.u = q.x << 16;         s0 += t.f;
      t.u = q.x & 0xFFFF0000u; s1 += t.f;
      t.u = q.y << 16;         s2 += t.f;
      t.u = q.y & 0xFFFF0000u; s3 += t.f;
      t.u = q.z << 16;         s4 += t.f;
      t.u = q.z & 0xFFFF0000u; s5 += t.f;
      t.u = q.w << 16;         s6 += t.f;
      t.u = q.w & 0xFFFF0000u; s7 += t.f;
    }
    s0 += __shfl_xor(s0, 4, 64);
    s1 += __shfl_xor(s1, 4, 64);
    s2 += __shfl_xor(s2, 4, 64);
    s3 += __shfl_xor(s3, 4, 64);
    s4 += __shfl_xor(s4, 4, 64);
    s5 += __shfl_xor(s5, 4, 64);
    s6 += __shfl_xor(s6, 4, 64);
    s7 += __shfl_xor(s7, 4, 64);
    if (rhalf == 0) {
      uint4 mo;
      mo.x = cvt_pk(s0, s1);
      mo.y = cvt_pk(s2, s3);
      mo.z = cvt_pk(s4, s5);
      mo.w = cvt_pk(s6, s7);
      *(uint4*)&ninLds[nl * NINS + FDIM + colq * 8] = mo;
    }
    float mx = 0, my = 0, mz = 0;
    for (int r = off + sub; r < end; r += 8) {
      float4 q = *(const float4*)&mh4[(size_t)r * 4];
      mx += q.x; my += q.y; mz += q.z;
    }
    mx += __shfl_xor(mx, 1, 64); mx += __shfl_xor(mx, 2, 64); mx += __shfl_xor(mx, 4, 64);
    my += __shfl_xor(my, 1, 64); my += __shfl_xor(my, 2, 64); my += __shfl_xor(my, 4, 64);
    mz += __shfl_xor(mz, 1, 64); mz += __shfl_xor(mz, 2, 64); mz += __shfl_xor(mz, 4, 64);
    if (sub == 0 && n < N_NODES) {
      Xout[n * XDIM + 0] = Xin[n * XDIM + 0] + mx;
      Xout[n * XDIM + 1] = Xin[n * XDIM + 1] + my;
      Xout[n * XDIM + 2] = Xin[n * XDIM + 2] + mz;
    }
  }
  __syncthreads();

  // M1: h1T = silu(nW1T . n_inT + nb1)
  const unsigned short* W1 = nw1t + layer * NH * NINS;
  const float* B1 = nb1 + layer * NH;
  for (int jt = wid; jt < 8; jt += 4) {
    f32x4 b4 = *(const f32x4*)&B1[jt * 16 + kg * 4];
    short8 a[3];
    #pragma unroll
    for (int ks = 0; ks < 3; ++ks)
      a[ks] = *(const short8*)&W1[(jt * 16 + ln15) * NINS + ks * 32 + kg * 8];
    #pragma unroll
    for (int et = 0; et < 4; ++et) {
      f32x4 acc = b4;
      #pragma unroll
      for (int ks = 0; ks < 3; ++ks) {
        short8 b = *(const short8*)&ninLds[(et * 16 + ln15) * NINS + ks * 32 + kg * 8];
        acc = __builtin_amdgcn_mfma_f32_16x16x32_bf16(a[ks], b, acc, 0, 0, 0);
      }
      uint2 uu;
      uu.x = cvt_pk(fsilu(acc[0]), fsilu(acc[1]));
      uu.y = cvt_pk(fsilu(acc[2]), fsilu(acc[3]));
      *(uint2*)&h1Lds[(et * 16 + ln15) * NH1S + jt * 16 + kg * 4] = uu;
    }
  }
  __syncthreads();

  // M2: outT = nW2T . h1T + nb2
  const unsigned short* W2 = nw2t + layer * FDIM * NW2K;
  const float* B2 = nb2 + layer * FDIM;
  f32x4 oacc[4];
  {
    int jt = wid;
    f32x4 b4 = *(const f32x4*)&B2[jt * 16 + kg * 4];
    short8 a[4];
    #pragma unroll
    for (int ks = 0; ks < 4; ++ks)
      a[ks] = *(const short8*)&W2[(jt * 16 + ln15) * NW2K + ks * 32 + kg * 8];
    #pragma unroll
    for (int et = 0; et < 4; ++et) {
      f32x4 acc = b4;
      #pragma unroll
      for (int ks = 0; ks < 4; ++ks) {
        short8 b = *(const short8*)&h1Lds[(et * 16 + ln15) * NH1S + ks * 32 + kg * 8];
        acc = __builtin_amdgcn_mfma_f32_16x16x32_bf16(a[ks], b, acc, 0, 0, 0);
      }
      oacc[et] = acc;
    }
  }
  __syncthreads();
  {
    int jt = wid;
    #pragma unroll
    for (int et = 0; et < 4; ++et)
      *(f32x4*)&outLds[(et * 16 + ln15) * 68 + jt * 16 + kg * 4] = oacc[et];
  }
  __syncthreads();

  #pragma unroll
  for (int it = 0; it < 16; ++it) {
    int idx = tid + it * 256;
    int nl = idx >> 6, c = idx & 63;
    int n = n0 + nl;
    if (n < N_NODES) {
      float v = Xin[n * XDIM + PDIM + c] + outLds[nl * 68 + c];
      Xout[n * XDIM + PDIM + c] = v;
      if (writeXb) XbOut[n * 64 + c] = f2bf(v);
    }
  }
}

extern "C" void kernel_launch(void* const* d_in, const int* in_sizes, int n_in,
                              void* d_out, int out_size, void* d_ws, size_t ws_size,
                              hipStream_t stream) {
  const float* x      = (const float*)d_in[0];
  const int*   ei     = (const int*)d_in[1];
  const float* eW1    = (const float*)d_in[2];
  const float* eb1    = (const float*)d_in[3];
  const float* eW2    = (const float*)d_in[4];
  const float* eb2    = (const float*)d_in[5];
  const float* cW1    = (const float*)d_in[6];
  const float* cb1    = (const float*)d_in[7];
  const float* cW2    = (const float*)d_in[8];
  const float* cb2    = (const float*)d_in[9];
  const float* nW1    = (const float*)d_in[10];
  const float* nb1    = (const float*)d_in[11];
  const float* nW2    = (const float*)d_in[12];
  const float* nb2    = (const float*)d_in[13];
  const float* cscale = (const float*)d_in[14];

  float* ws     = (float*)d_ws;
  float* X1     = ws;                                   // N*67 f32
  float* mh4    = X1 + N_NODES * XDIM;                  // E*4 f32
  int*   csr    = (int*)(mh4 + (size_t)N_EDGES * 4);    // N+4
  int*   cursor = csr + N_NODES + 4;                    // N
  int*   cnt    = cursor + N_NODES;                     // N
  int*   srcS   = cnt + N_NODES;                        // E
  int*   dstS   = srcS + N_EDGES;                       // E
  unsigned short* w1t  = (unsigned short*)(dstS + N_EDGES);
  unsigned short* w2t  = w1t + NLAYERS * H1T * W1T_K;
  unsigned short* cw1t = w2t + NLAYERS * MDIM * H1T;
  unsigned short* nw1t = cw1t + NLAYERS * CH * MDIM;
  unsigned short* nw2t = nw1t + NLAYERS * NH * NINS;
  float* b1p = (float*)(nw2t + NLAYERS * FDIM * NW2K);
  float* wrp = b1p + NLAYERS * H1T;
  unsigned short* Xb = (unsigned short*)(wrp + NLAYERS * H1T);  // N*64 bf16
  unsigned short* ms = Xb + (size_t)N_NODES * 64;               // E*32 bf16

  hipMemsetAsync(cnt, 0, N_NODES * sizeof(int), stream);
  setup_kernel<<<COUNT_BLOCKS + PREP_BLOCKS + CONV_BLOCKS, 256, 0, stream>>>(
      ei, cnt, eW1, eW2, cW1, eb1, nW1, nW2,
      w1t, w2t, cw1t, nw1t, nw2t, b1p, wrp, x, Xb);
  scan_kernel<<<1, 1024, 0, stream>>>(cnt, csr, cursor);
  rank_kernel<<<(N_EDGES + 255) / 256, 256, 0, stream>>>(ei, cursor, srcS, dstS);

  const int nodeBlocks = (N_NODES + 63) / 64;
  for (int l = 0; l < NLAYERS; ++l) {
    const float* Xin = (l == 0) ? x : X1;
    float* Xout = (l == 0) ? X1 : (float*)d_out;
    edge_mfma_kernel<<<N_EDGES / 128, 256, 0, stream>>>(
        Xin, Xb, srcS, dstS, w1t, b1p, wrp, w2t, eb2, cw1t, cb1, cW2, cb2, cscale,
        ms, mh4, l);
    node_mfma_kernel<<<nodeBlocks, 256, 0, stream>>>(
        Xin, Xb, ms, mh4, csr, nw1t, nb1, nw2t, nb2, Xout, Xb, (l == 0) ? 1 : 0, l);
  }
}

// Round 18
// 647.638 us; speedup vs baseline: 1.0994x; 1.0191x over previous
//
#include <hip/hip_runtime.h>

#define N_NODES 50000
#define N_EDGES 800000
#define PDIM 3
#define FDIM 64
#define MDIM 32
#define NLAYERS 2
#define EINDIM 129
#define H1 258
#define CH 128
#define NH 128
#define XDIM 67
#define H1T 288
#define HSTR2 40        // hLds col stride (bf16): 80B = 5 quanta (odd -> conflict-free b128)
#define W1T_K 136
#define MLSTR 40
#define NINS 104
#define NH1S 136
#define NW2K 128

typedef __attribute__((ext_vector_type(8))) short short8;
typedef __attribute__((ext_vector_type(4))) float f32x4;

#define LOG2E 1.4426950408889634f

__device__ __forceinline__ float fsilu(float x) {
  float e = __builtin_amdgcn_exp2f(-x * LOG2E);
  return x * __builtin_amdgcn_rcpf(1.0f + e);
}

__device__ __forceinline__ float ftanh(float x) {
  float xc = fminf(fmaxf(x, -15.0f), 15.0f);
  float E = __builtin_amdgcn_exp2f(2.0f * LOG2E * xc);
  return (E - 1.0f) * __builtin_amdgcn_rcpf(E + 1.0f);
}

__device__ __forceinline__ unsigned short f2bf(float f) {
  union { float f; unsigned u; } v; v.f = f;
  unsigned r = v.u + 0x7FFF + ((v.u >> 16) & 1);  // RNE
  return (unsigned short)(r >> 16);
}

__device__ __forceinline__ unsigned cvt_pk(float lo, float hi) {
  unsigned r;
  asm("v_cvt_pk_bf16_f32 %0, %1, %2" : "=v"(r) : "v"(lo), "v"(hi));
  return r;
}

// bijective XCD-chunk swizzle (m204)
__device__ __forceinline__ int xcd_swz(int bid, int nwg) {
  const int nx = 8;
  int q = nwg / nx, r = nwg % nx;
  int xcd = bid % nx, idx = bid / nx;
  return (xcd < r) ? xcd * (q + 1) + idx : r * (q + 1) + (xcd - r) * q + idx;
}

#define COUNT_BLOCKS 3125   // 800000/256
#define PREP_TOTAL (NLAYERS * (H1T * W1T_K + MDIM * H1T + CH * MDIM + 2 * H1T \
                               + NH * NINS + FDIM * NW2K))
#define PREP_BLOCKS ((PREP_TOTAL + 255) / 256)
#define CONV_BLOCKS ((N_NODES * 8 + 255) / 256)

// fused setup: count histogram + weight prep + X bf16 conversion
__global__ void setup_kernel(const int* __restrict__ ei, int* __restrict__ cnt,
                             const float* __restrict__ eW1, const float* __restrict__ eW2,
                             const float* __restrict__ cW1, const float* __restrict__ eb1,
                             const float* __restrict__ nW1, const float* __restrict__ nW2,
                             unsigned short* __restrict__ w1t, unsigned short* __restrict__ w2t,
                             unsigned short* __restrict__ cw1t,
                             unsigned short* __restrict__ nw1t, unsigned short* __restrict__ nw2t,
                             float* __restrict__ b1p, float* __restrict__ wrp,
                             const float* __restrict__ X, unsigned short* __restrict__ Xb) {
  const int bid = blockIdx.x;
  const int tid = threadIdx.x;
  if (bid < COUNT_BLOCKS) {
    int e = bid * 256 + tid;
    if (e < N_EDGES) atomicAdd(&cnt[ei[N_EDGES + e]], 1);
    return;
  }
  if (bid < COUNT_BLOCKS + PREP_BLOCKS) {
    int idx = (bid - COUNT_BLOCKS) * 256 + tid;
    const int n1 = NLAYERS * H1T * W1T_K;
    const int n2 = NLAYERS * MDIM * H1T;
    const int n3 = NLAYERS * CH * MDIM;
    const int n4 = NLAYERS * H1T;
    const int n5 = NLAYERS * NH * NINS;
    const int n6 = NLAYERS * FDIM * NW2K;
    if (idx < n1) {
      int k = idx % W1T_K;
      int rest = idx / W1T_K;
      int j = rest % H1T;
      int l = rest / H1T;
      float v = (k < 128 && j < H1) ? eW1[(l * EINDIM + k) * H1 + j] : 0.0f;
      w1t[idx] = f2bf(v);
    } else if (idx < n1 + n2) {
      int t = idx - n1;
      int k = t % H1T;
      int rest = t / H1T;
      int n = rest % MDIM;
      int l = rest / MDIM;
      float v = (k < H1) ? eW2[(l * H1 + k) * MDIM + n] : 0.0f;
      w2t[t] = f2bf(v);
    } else if (idx < n1 + n2 + n3) {
      int t = idx - n1 - n2;
      int k = t % MDIM;
      int rest = t / MDIM;
      int n = rest % CH;
      int l = rest / CH;
      cw1t[t] = f2bf(cW1[(l * MDIM + k) * CH + n]);
    } else if (idx < n1 + n2 + n3 + n4) {
      int t = idx - n1 - n2 - n3;
      int j = t % H1T;
      int l = t / H1T;
      b1p[t] = (j < H1) ? eb1[l * H1 + j] : 0.0f;
    } else if (idx < n1 + n2 + n3 + 2 * n4) {
      int t = idx - n1 - n2 - n3 - n4;
      int j = t % H1T;
      int l = t / H1T;
      wrp[t] = (j < H1) ? eW1[((size_t)l * EINDIM + 128) * H1 + j] : 0.0f;
    } else if (idx < n1 + n2 + n3 + 2 * n4 + n5) {
      int t = idx - n1 - n2 - n3 - 2 * n4;
      int k = t % NINS;
      int rest = t / NINS;
      int j = rest % NH;
      int l = rest / NH;
      float v = (k < FDIM + MDIM) ? nW1[(l * (FDIM + MDIM) + k) * NH + j] : 0.0f;
      nw1t[t] = f2bf(v);
    } else if (idx < n1 + n2 + n3 + 2 * n4 + n5 + n6) {
      int t = idx - n1 - n2 - n3 - 2 * n4 - n5;
      int k = t % NW2K;
      int rest = t / NW2K;
      int j = rest % FDIM;
      int l = rest / FDIM;
      nw2t[t] = f2bf(nW2[(l * NH + k) * FDIM + j]);
    }
    return;
  }
  {
    int idx = (bid - COUNT_BLOCKS - PREP_BLOCKS) * 256 + tid;
    if (idx >= N_NODES * 8) return;
    int n = idx >> 3, c = idx & 7;
    const float* src = X + n * XDIM + PDIM + c * 8;
    short8 v;
    #pragma unroll
    for (int i = 0; i < 8; ++i) v[i] = (short)f2bf(src[i]);
    *(short8*)&Xb[n * 64 + c * 8] = v;
  }
}

__global__ __launch_bounds__(1024)
void scan_kernel(const int* __restrict__ cnt, int* __restrict__ csr, int* __restrict__ cursor) {
  __shared__ int partial[1024];
  const int tid = threadIdx.x;
  const int CHUNK = 49;
  int base = tid * CHUNK;
  int s = 0;
  for (int i = 0; i < CHUNK; ++i) {
    int idx = base + i;
    if (idx < N_NODES) s += cnt[idx];
  }
  partial[tid] = s;
  __syncthreads();
  for (int off = 1; off < 1024; off <<= 1) {
    int v = (tid >= off) ? partial[tid - off] : 0;
    __syncthreads();
    partial[tid] += v;
    __syncthreads();
  }
  int run = partial[tid] - s;
  for (int i = 0; i < CHUNK; ++i) {
    int idx = base + i;
    if (idx < N_NODES) {
      csr[idx] = run;
      cursor[idx] = run;
      run += cnt[idx];
    }
  }
  if (tid == 1023) csr[N_NODES] = run;
}

__global__ void rank_kernel(const int* __restrict__ ei, int* __restrict__ cursor,
                            int* __restrict__ srcS, int* __restrict__ dstS) {
  int e = blockIdx.x * 256 + threadIdx.x;
  if (e < N_EDGES) {
    int s = ei[e];
    int d = ei[N_EDGES + e];
    int p = atomicAdd(&cursor[d], 1);
    srcS[p] = s;
    dstS[p] = d;
  }
}

// Edge kernel v7: same as best-known R15/R17 but 17 j-tiles instead of 18
// (tile 17 was 100% zero padding: H1=258 fits in 272 cols). Epilogue chunk
// computes tile 16 + zero-fills the chunk buffer's upper half.
__global__ __launch_bounds__(256, 4)
void edge_mfma_kernel(const float* __restrict__ X,
                      const unsigned short* __restrict__ Xb,
                      const int* __restrict__ srcS, const int* __restrict__ dstS,
                      const unsigned short* __restrict__ w1t,
                      const float* __restrict__ b1p, const float* __restrict__ wrp,
                      const unsigned short* __restrict__ w2t, const float* __restrict__ eb2,
                      const unsigned short* __restrict__ cw1t, const float* __restrict__ cb1,
                      const float* __restrict__ cW2, const float* __restrict__ cb2,
                      const float* __restrict__ cscale,
                      unsigned short* __restrict__ ms, float* __restrict__ mh4,
                      int layer)
{
  __shared__ unsigned short hLds[128 * HSTR2];  // 10240 B, wave-partitioned rows
  __shared__ unsigned short ml[128 * MLSTR];    // 10240 B

  const int tid = threadIdx.x;
  const int lane = tid & 63;
  const int wid = tid >> 6;
  const int ln15 = lane & 15;
  const int kg = lane >> 4;
  const int e0 = xcd_swz(blockIdx.x, gridDim.x) * 128;
  const int ew0 = e0 + wid * 32;

  const int eA = ew0 + ln15;
  const int eB = ew0 + 16 + ln15;
  const int sA = srcS[eA], dA = dstS[eA];
  const int sB = srcS[eB], dB = dstS[eB];
  float rxA = X[sA * XDIM + 0] - X[dA * XDIM + 0];
  float ryA = X[sA * XDIM + 1] - X[dA * XDIM + 1];
  float rzA = X[sA * XDIM + 2] - X[dA * XDIM + 2];
  float rxB = X[sB * XDIM + 0] - X[dB * XDIM + 0];
  float ryB = X[sB * XDIM + 1] - X[dB * XDIM + 1];
  float rzB = X[sB * XDIM + 2] - X[dB * XDIM + 2];
  const float distA = rxA * rxA + ryA * ryA + rzA * rzA;
  const float distB = rxB * rxB + ryB * ryB + rzB * rzB;

  short8 einB[2][4];
  #pragma unroll
  for (int ks = 0; ks < 4; ++ks) {
    int nA = (ks < 2) ? dA : sA;
    int nB = (ks < 2) ? dB : sB;
    einB[0][ks] = *(const short8*)&Xb[nA * 64 + (ks & 1) * 32 + kg * 8];
    einB[1][ks] = *(const short8*)&Xb[nB * 64 + (ks & 1) * 32 + kg * 8];
  }

  const unsigned short* W1T = w1t + layer * H1T * W1T_K;
  const float* B1P = b1p + layer * H1T;
  const float* WRP = wrp + layer * H1T;
  const unsigned short* W2T = w2t + layer * MDIM * H1T;
  const float* B2 = eb2 + layer * MDIM;

  float b20 = B2[ln15], b21 = B2[16 + ln15];
  f32x4 mac[2][2];
  #pragma unroll
  for (int et = 0; et < 2; ++et) {
    mac[et][0] = (f32x4){b20, b20, b20, b20};
    mac[et][1] = (f32x4){b21, b21, b21, b21};
  }

  // ---- 8 chunks of 32 h-cols (j-tiles 0..15); B then C per chunk ----
  #pragma unroll 1
  for (int chunk = 0; chunk < 8; ++chunk) {
    #pragma unroll
    for (int jl = 0; jl < 2; ++jl) {
      const int jt = chunk * 2 + jl;
      f32x4 b4 = *(const f32x4*)&B1P[jt * 16 + kg * 4];
      f32x4 w4 = *(const f32x4*)&WRP[jt * 16 + kg * 4];
      short8 a[4];
      #pragma unroll
      for (int ks = 0; ks < 4; ++ks)
        a[ks] = *(const short8*)&W1T[(jt * 16 + ln15) * W1T_K + ks * 32 + kg * 8];
      #pragma unroll
      for (int et = 0; et < 2; ++et) {
        const float dv = et ? distB : distA;
        f32x4 acc;
        #pragma unroll
        for (int r = 0; r < 4; ++r) acc[r] = fmaf(dv, w4[r], b4[r]);
        #pragma unroll
        for (int ks = 0; ks < 4; ++ks)
          acc = __builtin_amdgcn_mfma_f32_16x16x32_bf16(a[ks], einB[et][ks], acc, 0, 0, 0);
        uint2 uu;
        uu.x = cvt_pk(fsilu(acc[0]), fsilu(acc[1]));
        uu.y = cvt_pk(fsilu(acc[2]), fsilu(acc[3]));
        *(uint2*)&hLds[(wid * 32 + et * 16 + ln15) * HSTR2 + jl * 16 + kg * 4] = uu;
      }
    }
    // phase C partial: this chunk's 32 k values
    {
      const int kglob = chunk * 32;
      short8 w0 = *(const short8*)&W2T[ln15 * H1T + kglob + kg * 8];
      short8 w1 = *(const short8*)&W2T[(16 + ln15) * H1T + kglob + kg * 8];
      #pragma unroll
      for (int et = 0; et < 2; ++et) {
        short8 ah = *(const short8*)&hLds[(wid * 32 + et * 16 + ln15) * HSTR2 + kg * 8];
        mac[et][0] = __builtin_amdgcn_mfma_f32_16x16x32_bf16(ah, w0, mac[et][0], 0, 0, 0);
        mac[et][1] = __builtin_amdgcn_mfma_f32_16x16x32_bf16(ah, w1, mac[et][1], 0, 0, 0);
      }
    }
  }
  // ---- epilogue chunk: j-tile 16 (cols 256-271; 256,257 real) + zero pad ----
  {
    const int jt = 16;
    f32x4 b4 = *(const f32x4*)&B1P[jt * 16 + kg * 4];
    f32x4 w4 = *(const f32x4*)&WRP[jt * 16 + kg * 4];
    short8 a[4];
    #pragma unroll
    for (int ks = 0; ks < 4; ++ks)
      a[ks] = *(const short8*)&W1T[(jt * 16 + ln15) * W1T_K + ks * 32 + kg * 8];
    #pragma unroll
    for (int et = 0; et < 2; ++et) {
      const float dv = et ? distB : distA;
      f32x4 acc;
      #pragma unroll
      for (int r = 0; r < 4; ++r) acc[r] = fmaf(dv, w4[r], b4[r]);
      #pragma unroll
      for (int ks = 0; ks < 4; ++ks)
        acc = __builtin_amdgcn_mfma_f32_16x16x32_bf16(a[ks], einB[et][ks], acc, 0, 0, 0);
      uint2 uu;
      uu.x = cvt_pk(fsilu(acc[0]), fsilu(acc[1]));
      uu.y = cvt_pk(fsilu(acc[2]), fsilu(acc[3]));
      *(uint2*)&hLds[(wid * 32 + et * 16 + ln15) * HSTR2 + kg * 4] = uu;
      // zero the upper 16 cols of the chunk buffer (replaces all-padding tile 17)
      uint2 zz; zz.x = 0u; zz.y = 0u;
      *(uint2*)&hLds[(wid * 32 + et * 16 + ln15) * HSTR2 + 16 + kg * 4] = zz;
    }
    // phase C: cols 256..287 (>=258 are zeros in W2T / zeroed hLds)
    {
      const int kglob = 256;
      short8 w0 = *(const short8*)&W2T[ln15 * H1T + kglob + kg * 8];
      short8 w1 = *(const short8*)&W2T[(16 + ln15) * H1T + kglob + kg * 8];
      #pragma unroll
      for (int et = 0; et < 2; ++et) {
        short8 ah = *(const short8*)&hLds[(wid * 32 + et * 16 + ln15) * HSTR2 + kg * 8];
        mac[et][0] = __builtin_amdgcn_mfma_f32_16x16x32_bf16(ah, w0, mac[et][0], 0, 0, 0);
        mac[et][1] = __builtin_amdgcn_mfma_f32_16x16x32_bf16(ah, w1, mac[et][1], 0, 0, 0);
      }
    }
  }

  #pragma unroll
  for (int et = 0; et < 2; ++et) {
    #pragma unroll
    for (int r = 0; r < 4; ++r) {
      int eg = wid * 32 + et * 16 + kg * 4 + r;
      ml[eg * MLSTR + ln15] = f2bf(fsilu(mac[et][0][r]));
      ml[eg * MLSTR + 16 + ln15] = f2bf(fsilu(mac[et][1][r]));
    }
  }

  const unsigned short* CW1T = cw1t + layer * CH * MDIM;
  const float* CB1 = cb1 + layer * CH;
  const float* CW2v = cW2 + layer * CH;
  short8 amA = *(const short8*)&ml[(wid * 32 + ln15) * MLSTR + kg * 8];
  short8 amB = *(const short8*)&ml[(wid * 32 + 16 + ln15) * MLSTR + kg * 8];
  float psA[4] = {0.f, 0.f, 0.f, 0.f};
  float psB[4] = {0.f, 0.f, 0.f, 0.f};
  #pragma unroll
  for (int nt = 0; nt < 8; ++nt) {
    float cb = CB1[nt * 16 + ln15];
    float w2v = CW2v[nt * 16 + ln15];
    short8 bc = *(const short8*)&CW1T[(nt * 16 + ln15) * MDIM + kg * 8];
    f32x4 cA = {cb, cb, cb, cb};
    f32x4 cB = {cb, cb, cb, cb};
    cA = __builtin_amdgcn_mfma_f32_16x16x32_bf16(amA, bc, cA, 0, 0, 0);
    cB = __builtin_amdgcn_mfma_f32_16x16x32_bf16(amB, bc, cB, 0, 0, 0);
    #pragma unroll
    for (int r = 0; r < 4; ++r) {
      psA[r] += fsilu(cA[r]) * w2v;
      psB[r] += fsilu(cB[r]) * w2v;
    }
  }
  #pragma unroll
  for (int off = 1; off < 16; off <<= 1) {
    #pragma unroll
    for (int r = 0; r < 4; ++r) {
      psA[r] += __shfl_xor(psA[r], off, 64);
      psB[r] += __shfl_xor(psB[r], off, 64);
    }
  }
  float cwvA = 0.0f, cwvB = 0.0f;
  #pragma unroll
  for (int r = 0; r < 4; ++r) {
    float tA = __shfl(psA[r], ((lane & 15) >> 2) * 16, 64);
    float tB = __shfl(psB[r], ((lane & 15) >> 2) * 16, 64);
    if ((lane & 3) == r) { cwvA = tA; cwvB = tB; }
  }

  #pragma unroll
  for (int it = 0; it < 2; ++it) {
    int idx = lane + it * 64;
    int el = idx >> 2, seg = idx & 3;
    short8 v = *(const short8*)&ml[(wid * 32 + el) * MLSTR + seg * 8];
    *(short8*)&ms[(size_t)(ew0 + el) * MDIM + seg * 8] = v;
  }
  if (lane < 32) {
    const int hi = lane >> 4;
    float cwv = hi ? cwvB : cwvA;
    float dv = hi ? distB : distA;
    float rx = hi ? rxB : rxA, ry = hi ? ryB : ryA, rz = hi ? rzB : rzA;
    float cw = ftanh(cwv + cb2[layer]);
    float fac = cw * cscale[layer] / fmaxf(sqrtf(dv), 1e-8f);
    *(float4*)&mh4[(size_t)(ew0 + lane) * 4] = make_float4(fac * rx, fac * ry, fac * rz, 0.0f);
  }
}

// ---- MFMA node kernel v3 (best-known) ----
__global__ __launch_bounds__(256, 5)
void node_mfma_kernel(const float* __restrict__ Xin,
                      const unsigned short* __restrict__ XbIn,
                      const unsigned short* __restrict__ ms,
                      const float* __restrict__ mh4,
                      const int* __restrict__ csr,
                      const unsigned short* __restrict__ nw1t, const float* __restrict__ nb1,
                      const unsigned short* __restrict__ nw2t, const float* __restrict__ nb2,
                      float* __restrict__ Xout, unsigned short* __restrict__ XbOut,
                      int writeXb, int layer)
{
  __shared__ unsigned short ninLds[64 * NINS];  // 13312 B
  __shared__ unsigned short h1Lds[64 * NH1S];   // 17408 B, reused as f32 out[64][68]
  __shared__ int csrLds[65];
  float* outLds = (float*)h1Lds;

  const int tid = threadIdx.x;
  const int lane = tid & 63;
  const int wid = tid >> 6;
  const int ln15 = lane & 15;
  const int kg = lane >> 4;
  const int n0 = xcd_swz(blockIdx.x, gridDim.x) * 64;

  if (tid < 65) {
    int nn = n0 + tid;
    csrLds[tid] = (nn <= N_NODES) ? csr[nn] : 0;
  }
  #pragma unroll
  for (int it = 0; it < 2; ++it) {
    int idx = tid + it * 256;
    int nl = idx >> 3, c = idx & 7;
    int n = n0 + nl;
    uint4 v = make_uint4(0, 0, 0, 0);
    if (n < N_NODES) v = *(const uint4*)&XbIn[n * 64 + c * 8];
    *(uint4*)&ninLds[nl * NINS + c * 8] = v;
  }
  __syncthreads();

  // gather m_i + mhat: 8 threads/node, 2 passes
  #pragma unroll 1
  for (int pass = 0; pass < 2; ++pass) {
    const int nl = (tid >> 3) + pass * 32;
    const int sub = tid & 7;
    const int colq = sub & 3;
    const int rhalf = sub >> 2;
    const int n = n0 + nl;
    int off = csrLds[nl], end = csrLds[nl + 1];
    if (n >= N_NODES) { off = 0; end = 0; }
    float s0 = 0, s1 = 0, s2 = 0, s3 = 0, s4 = 0, s5 = 0, s6 = 0, s7 = 0;
    for (int r = off + rhalf; r < end; r += 2) {
      uint4 q = *(const uint4*)&ms[(size_t)r * MDIM + colq * 8];
      union { unsigned u; float f; } t;
      t.u = q.x << 16;         s0 += t.f;
      t.u = q.x & 0xFFFF0000u; s1 += t.f;
      t.u = q.y << 16;         s2 += t.f;
      t.u = q.y & 0xFFFF0000u; s3 += t.f;
      t.u = q.z << 16;         s4 += t.f;
      t.u = q.z & 0xFFFF0000u; s5 += t.f;
      t.u = q.w << 16;         s6 += t.f;
      t.u = q.w & 0xFFFF0000u; s7 += t.f;
    }
    s0 += __shfl_xor(s0, 4, 64);
    s1 += __shfl_xor(s1, 4, 64);
    s2 += __shfl_xor(s2, 4, 64);
    s3 += __shfl_xor(s3, 4, 64);
    s4 += __shfl_xor(s4, 4, 64);
    s5 += __shfl_xor(s5, 4, 64);
    s6 += __shfl_xor(s6, 4, 64);
    s7 += __shfl_xor(s7, 4, 64);
    if (rhalf == 0) {
      uint4 mo;
      mo.x = cvt_pk(s0, s1);
      mo.y = cvt_pk(s2, s3);
      mo.z = cvt_pk(s4, s5);
      mo.w = cvt_pk(s6, s7);
      *(uint4*)&ninLds[nl * NINS + FDIM + colq * 8] = mo;
    }
    float mx = 0, my = 0, mz = 0;
    for (int r = off + sub; r < end; r += 8) {
      float4 q = *(const float4*)&mh4[(size_t)r * 4];
      mx += q.x; my += q.y; mz += q.z;
    }
    mx += __shfl_xor(mx, 1, 64); mx += __shfl_xor(mx, 2, 64); mx += __shfl_xor(mx, 4, 64);
    my += __shfl_xor(my, 1, 64); my += __shfl_xor(my, 2, 64); my += __shfl_xor(my, 4, 64);
    mz += __shfl_xor(mz, 1, 64); mz += __shfl_xor(mz, 2, 64); mz += __shfl_xor(mz, 4, 64);
    if (sub == 0 && n < N_NODES) {
      Xout[n * XDIM + 0] = Xin[n * XDIM + 0] + mx;
      Xout[n * XDIM + 1] = Xin[n * XDIM + 1] + my;
      Xout[n * XDIM + 2] = Xin[n * XDIM + 2] + mz;
    }
  }
  __syncthreads();

  // M1: h1T = silu(nW1T . n_inT + nb1)
  const unsigned short* W1 = nw1t + layer * NH * NINS;
  const float* B1 = nb1 + layer * NH;
  for (int jt = wid; jt < 8; jt += 4) {
    f32x4 b4 = *(const f32x4*)&B1[jt * 16 + kg * 4];
    short8 a[3];
    #pragma unroll
    for (int ks = 0; ks < 3; ++ks)
      a[ks] = *(const short8*)&W1[(jt * 16 + ln15) * NINS + ks * 32 + kg * 8];
    #pragma unroll
    for (int et = 0; et < 4; ++et) {
      f32x4 acc = b4;
      #pragma unroll
      for (int ks = 0; ks < 3; ++ks) {
        short8 b = *(const short8*)&ninLds[(et * 16 + ln15) * NINS + ks * 32 + kg * 8];
        acc = __builtin_amdgcn_mfma_f32_16x16x32_bf16(a[ks], b, acc, 0, 0, 0);
      }
      uint2 uu;
      uu.x = cvt_pk(fsilu(acc[0]), fsilu(acc[1]));
      uu.y = cvt_pk(fsilu(acc[2]), fsilu(acc[3]));
      *(uint2*)&h1Lds[(et * 16 + ln15) * NH1S + jt * 16 + kg * 4] = uu;
    }
  }
  __syncthreads();

  // M2: outT = nW2T . h1T + nb2
  const unsigned short* W2 = nw2t + layer * FDIM * NW2K;
  const float* B2 = nb2 + layer * FDIM;
  f32x4 oacc[4];
  {
    int jt = wid;
    f32x4 b4 = *(const f32x4*)&B2[jt * 16 + kg * 4];
    short8 a[4];
    #pragma unroll
    for (int ks = 0; ks < 4; ++ks)
      a[ks] = *(const short8*)&W2[(jt * 16 + ln15) * NW2K + ks * 32 + kg * 8];
    #pragma unroll
    for (int et = 0; et < 4; ++et) {
      f32x4 acc = b4;
      #pragma unroll
      for (int ks = 0; ks < 4; ++ks) {
        short8 b = *(const short8*)&h1Lds[(et * 16 + ln15) * NH1S + ks * 32 + kg * 8];
        acc = __builtin_amdgcn_mfma_f32_16x16x32_bf16(a[ks], b, acc, 0, 0, 0);
      }
      oacc[et] = acc;
    }
  }
  __syncthreads();
  {
    int jt = wid;
    #pragma unroll
    for (int et = 0; et < 4; ++et)
      *(f32x4*)&outLds[(et * 16 + ln15) * 68 + jt * 16 + kg * 4] = oacc[et];
  }
  __syncthreads();

  #pragma unroll
  for (int it = 0; it < 16; ++it) {
    int idx = tid + it * 256;
    int nl = idx >> 6, c = idx & 63;
    int n = n0 + nl;
    if (n < N_NODES) {
      float v = Xin[n * XDIM + PDIM + c] + outLds[nl * 68 + c];
      Xout[n * XDIM + PDIM + c] = v;
      if (writeXb) XbOut[n * 64 + c] = f2bf(v);
    }
  }
}

extern "C" void kernel_launch(void* const* d_in, const int* in_sizes, int n_in,
                              void* d_out, int out_size, void* d_ws, size_t ws_size,
                              hipStream_t stream) {
  const float* x      = (const float*)d_in[0];
  const int*   ei     = (const int*)d_in[1];
  const float* eW1    = (const float*)d_in[2];
  const float* eb1    = (const float*)d_in[3];
  const float* eW2    = (const float*)d_in[4];
  const float* eb2    = (const float*)d_in[5];
  const float* cW1    = (const float*)d_in[6];
  const float* cb1    = (const float*)d_in[7];
  const float* cW2    = (const float*)d_in[8];
  const float* cb2    = (const float*)d_in[9];
  const float* nW1    = (const float*)d_in[10];
  const float* nb1    = (const float*)d_in[11];
  const float* nW2    = (const float*)d_in[12];
  const float* nb2    = (const float*)d_in[13];
  const float* cscale = (const float*)d_in[14];

  float* ws     = (float*)d_ws;
  float* X1     = ws;                                   // N*67 f32
  float* mh4    = X1 + N_NODES * XDIM;                  // E*4 f32
  int*   csr    = (int*)(mh4 + (size_t)N_EDGES * 4);    // N+4
  int*   cursor = csr + N_NODES + 4;                    // N
  int*   cnt    = cursor + N_NODES;                     // N
  int*   srcS   = cnt + N_NODES;                        // E
  int*   dstS   = srcS + N_EDGES;                       // E
  unsigned short* w1t  = (unsigned short*)(dstS + N_EDGES);
  unsigned short* w2t  = w1t + NLAYERS * H1T * W1T_K;
  unsigned short* cw1t = w2t + NLAYERS * MDIM * H1T;
  unsigned short* nw1t = cw1t + NLAYERS * CH * MDIM;
  unsigned short* nw2t = nw1t + NLAYERS * NH * NINS;
  float* b1p = (float*)(nw2t + NLAYERS * FDIM * NW2K);
  float* wrp = b1p + NLAYERS * H1T;
  unsigned short* Xb = (unsigned short*)(wrp + NLAYERS * H1T);  // N*64 bf16
  unsigned short* ms = Xb + (size_t)N_NODES * 64;               // E*32 bf16

  hipMemsetAsync(cnt, 0, N_NODES * sizeof(int), stream);
  setup_kernel<<<COUNT_BLOCKS + PREP_BLOCKS + CONV_BLOCKS, 256, 0, stream>>>(
      ei, cnt, eW1, eW2, cW1, eb1, nW1, nW2,
      w1t, w2t, cw1t, nw1t, nw2t, b1p, wrp, x, Xb);
  scan_kernel<<<1, 1024, 0, stream>>>(cnt, csr, cursor);
  rank_kernel<<<(N_EDGES + 255) / 256, 256, 0, stream>>>(ei, cursor, srcS, dstS);

  const int nodeBlocks = (N_NODES + 63) / 64;
  for (int l = 0; l < NLAYERS; ++l) {
    const float* Xin = (l == 0) ? x : X1;
    float* Xout = (l == 0) ? X1 : (float*)d_out;
    edge_mfma_kernel<<<N_EDGES / 128, 256, 0, stream>>>(
        Xin, Xb, srcS, dstS, w1t, b1p, wrp, w2t, eb2, cw1t, cb1, cW2, cb2, cscale,
        ms, mh4, l);
    node_mfma_kernel<<<nodeBlocks, 256, 0, stream>>>(
        Xin, Xb, ms, mh4, csr, nw1t, nb1, nw2t, nb2, Xout, Xb, (l == 0) ? 1 : 0, l);
  }
}

// Round 19
// 635.081 us; speedup vs baseline: 1.1211x; 1.0198x over previous
//
#include <hip/hip_runtime.h>

#define N_NODES 50000
#define N_EDGES 800000
#define PDIM 3
#define FDIM 64
#define MDIM 32
#define NLAYERS 2
#define EINDIM 129
#define H1 258
#define CH 128
#define NH 128
#define XDIM 67
#define H1T 288
#define HSTR2 40        // hLds col stride (bf16): 80B = 5 quanta (odd -> conflict-free b128)
#define W1T_K 136
#define MLSTR 40
#define NINS 104
#define NH1S 136
#define NW2K 128

typedef __attribute__((ext_vector_type(8))) short short8;
typedef __attribute__((ext_vector_type(4))) float f32x4;

#define LOG2E 1.4426950408889634f

__device__ __forceinline__ float fsilu(float x) {
  float e = __builtin_amdgcn_exp2f(-x * LOG2E);
  return x * __builtin_amdgcn_rcpf(1.0f + e);
}

__device__ __forceinline__ float ftanh(float x) {
  float xc = fminf(fmaxf(x, -15.0f), 15.0f);
  float E = __builtin_amdgcn_exp2f(2.0f * LOG2E * xc);
  return (E - 1.0f) * __builtin_amdgcn_rcpf(E + 1.0f);
}

__device__ __forceinline__ unsigned short f2bf(float f) {
  union { float f; unsigned u; } v; v.f = f;
  unsigned r = v.u + 0x7FFF + ((v.u >> 16) & 1);  // RNE
  return (unsigned short)(r >> 16);
}

__device__ __forceinline__ unsigned cvt_pk(float lo, float hi) {
  unsigned r;
  asm("v_cvt_pk_bf16_f32 %0, %1, %2" : "=v"(r) : "v"(lo), "v"(hi));
  return r;
}

// bijective XCD-chunk swizzle (m204)
__device__ __forceinline__ int xcd_swz(int bid, int nwg) {
  const int nx = 8;
  int q = nwg / nx, r = nwg % nx;
  int xcd = bid % nx, idx = bid / nx;
  return (xcd < r) ? xcd * (q + 1) + idx : r * (q + 1) + (xcd - r) * q + idx;
}

#define COUNT_BLOCKS 3125   // 800000/256
#define PREP_TOTAL (NLAYERS * (H1T * W1T_K + MDIM * H1T + CH * MDIM + 2 * H1T \
                               + NH * NINS + FDIM * NW2K))
#define PREP_BLOCKS ((PREP_TOTAL + 255) / 256)
#define CONV_BLOCKS ((N_NODES * 8 + 255) / 256)

// fused setup: count histogram + weight prep + X bf16 conversion
__global__ void setup_kernel(const int* __restrict__ ei, int* __restrict__ cnt,
                             const float* __restrict__ eW1, const float* __restrict__ eW2,
                             const float* __restrict__ cW1, const float* __restrict__ eb1,
                             const float* __restrict__ nW1, const float* __restrict__ nW2,
                             unsigned short* __restrict__ w1t, unsigned short* __restrict__ w2t,
                             unsigned short* __restrict__ cw1t,
                             unsigned short* __restrict__ nw1t, unsigned short* __restrict__ nw2t,
                             float* __restrict__ b1p, float* __restrict__ wrp,
                             const float* __restrict__ X, unsigned short* __restrict__ Xb) {
  const int bid = blockIdx.x;
  const int tid = threadIdx.x;
  if (bid < COUNT_BLOCKS) {
    int e = bid * 256 + tid;
    if (e < N_EDGES) atomicAdd(&cnt[ei[N_EDGES + e]], 1);
    return;
  }
  if (bid < COUNT_BLOCKS + PREP_BLOCKS) {
    int idx = (bid - COUNT_BLOCKS) * 256 + tid;
    const int n1 = NLAYERS * H1T * W1T_K;
    const int n2 = NLAYERS * MDIM * H1T;
    const int n3 = NLAYERS * CH * MDIM;
    const int n4 = NLAYERS * H1T;
    const int n5 = NLAYERS * NH * NINS;
    const int n6 = NLAYERS * FDIM * NW2K;
    if (idx < n1) {
      int k = idx % W1T_K;
      int rest = idx / W1T_K;
      int j = rest % H1T;
      int l = rest / H1T;
      float v = (k < 128 && j < H1) ? eW1[(l * EINDIM + k) * H1 + j] : 0.0f;
      w1t[idx] = f2bf(v);
    } else if (idx < n1 + n2) {
      int t = idx - n1;
      int k = t % H1T;
      int rest = t / H1T;
      int n = rest % MDIM;
      int l = rest / MDIM;
      float v = (k < H1) ? eW2[(l * H1 + k) * MDIM + n] : 0.0f;
      w2t[t] = f2bf(v);
    } else if (idx < n1 + n2 + n3) {
      int t = idx - n1 - n2;
      int k = t % MDIM;
      int rest = t / MDIM;
      int n = rest % CH;
      int l = rest / CH;
      cw1t[t] = f2bf(cW1[(l * MDIM + k) * CH + n]);
    } else if (idx < n1 + n2 + n3 + n4) {
      int t = idx - n1 - n2 - n3;
      int j = t % H1T;
      int l = t / H1T;
      b1p[t] = (j < H1) ? eb1[l * H1 + j] : 0.0f;
    } else if (idx < n1 + n2 + n3 + 2 * n4) {
      int t = idx - n1 - n2 - n3 - n4;
      int j = t % H1T;
      int l = t / H1T;
      wrp[t] = (j < H1) ? eW1[((size_t)l * EINDIM + 128) * H1 + j] : 0.0f;
    } else if (idx < n1 + n2 + n3 + 2 * n4 + n5) {
      int t = idx - n1 - n2 - n3 - 2 * n4;
      int k = t % NINS;
      int rest = t / NINS;
      int j = rest % NH;
      int l = rest / NH;
      float v = (k < FDIM + MDIM) ? nW1[(l * (FDIM + MDIM) + k) * NH + j] : 0.0f;
      nw1t[t] = f2bf(v);
    } else if (idx < n1 + n2 + n3 + 2 * n4 + n5 + n6) {
      int t = idx - n1 - n2 - n3 - 2 * n4 - n5;
      int k = t % NW2K;
      int rest = t / NW2K;
      int j = rest % FDIM;
      int l = rest / FDIM;
      nw2t[t] = f2bf(nW2[(l * NH + k) * FDIM + j]);
    }
    return;
  }
  {
    int idx = (bid - COUNT_BLOCKS - PREP_BLOCKS) * 256 + tid;
    if (idx >= N_NODES * 8) return;
    int n = idx >> 3, c = idx & 7;
    const float* src = X + n * XDIM + PDIM + c * 8;
    short8 v;
    #pragma unroll
    for (int i = 0; i < 8; ++i) v[i] = (short)f2bf(src[i]);
    *(short8*)&Xb[n * 64 + c * 8] = v;
  }
}

__global__ __launch_bounds__(1024)
void scan_kernel(const int* __restrict__ cnt, int* __restrict__ csr, int* __restrict__ cursor) {
  __shared__ int partial[1024];
  const int tid = threadIdx.x;
  const int CHUNK = 49;
  int base = tid * CHUNK;
  int s = 0;
  for (int i = 0; i < CHUNK; ++i) {
    int idx = base + i;
    if (idx < N_NODES) s += cnt[idx];
  }
  partial[tid] = s;
  __syncthreads();
  for (int off = 1; off < 1024; off <<= 1) {
    int v = (tid >= off) ? partial[tid - off] : 0;
    __syncthreads();
    partial[tid] += v;
    __syncthreads();
  }
  int run = partial[tid] - s;
  for (int i = 0; i < CHUNK; ++i) {
    int idx = base + i;
    if (idx < N_NODES) {
      csr[idx] = run;
      cursor[idx] = run;
      run += cnt[idx];
    }
  }
  if (tid == 1023) csr[N_NODES] = run;
}

__global__ void rank_kernel(const int* __restrict__ ei, int* __restrict__ cursor,
                            int* __restrict__ srcS, int* __restrict__ dstS) {
  int e = blockIdx.x * 256 + threadIdx.x;
  if (e < N_EDGES) {
    int s = ei[e];
    int d = ei[N_EDGES + e];
    int p = atomicAdd(&cursor[d], 1);
    srcS[p] = s;
    dstS[p] = d;
  }
}

// Edge kernel v8: R18 (17-tile trim) + T5 s_setprio around MFMA clusters.
// No barriers -> waves drift across phases independently, the regime where
// setprio helped attn (+4-7%, m191) vs null on lockstep GEMM (m190).
__global__ __launch_bounds__(256, 4)
void edge_mfma_kernel(const float* __restrict__ X,
                      const unsigned short* __restrict__ Xb,
                      const int* __restrict__ srcS, const int* __restrict__ dstS,
                      const unsigned short* __restrict__ w1t,
                      const float* __restrict__ b1p, const float* __restrict__ wrp,
                      const unsigned short* __restrict__ w2t, const float* __restrict__ eb2,
                      const unsigned short* __restrict__ cw1t, const float* __restrict__ cb1,
                      const float* __restrict__ cW2, const float* __restrict__ cb2,
                      const float* __restrict__ cscale,
                      unsigned short* __restrict__ ms, float* __restrict__ mh4,
                      int layer)
{
  __shared__ unsigned short hLds[128 * HSTR2];  // 10240 B, wave-partitioned rows
  __shared__ unsigned short ml[128 * MLSTR];    // 10240 B

  const int tid = threadIdx.x;
  const int lane = tid & 63;
  const int wid = tid >> 6;
  const int ln15 = lane & 15;
  const int kg = lane >> 4;
  const int e0 = xcd_swz(blockIdx.x, gridDim.x) * 128;
  const int ew0 = e0 + wid * 32;

  const int eA = ew0 + ln15;
  const int eB = ew0 + 16 + ln15;
  const int sA = srcS[eA], dA = dstS[eA];
  const int sB = srcS[eB], dB = dstS[eB];
  float rxA = X[sA * XDIM + 0] - X[dA * XDIM + 0];
  float ryA = X[sA * XDIM + 1] - X[dA * XDIM + 1];
  float rzA = X[sA * XDIM + 2] - X[dA * XDIM + 2];
  float rxB = X[sB * XDIM + 0] - X[dB * XDIM + 0];
  float ryB = X[sB * XDIM + 1] - X[dB * XDIM + 1];
  float rzB = X[sB * XDIM + 2] - X[dB * XDIM + 2];
  const float distA = rxA * rxA + ryA * ryA + rzA * rzA;
  const float distB = rxB * rxB + ryB * ryB + rzB * rzB;

  short8 einB[2][4];
  #pragma unroll
  for (int ks = 0; ks < 4; ++ks) {
    int nA = (ks < 2) ? dA : sA;
    int nB = (ks < 2) ? dB : sB;
    einB[0][ks] = *(const short8*)&Xb[nA * 64 + (ks & 1) * 32 + kg * 8];
    einB[1][ks] = *(const short8*)&Xb[nB * 64 + (ks & 1) * 32 + kg * 8];
  }

  const unsigned short* W1T = w1t + layer * H1T * W1T_K;
  const float* B1P = b1p + layer * H1T;
  const float* WRP = wrp + layer * H1T;
  const unsigned short* W2T = w2t + layer * MDIM * H1T;
  const float* B2 = eb2 + layer * MDIM;

  float b20 = B2[ln15], b21 = B2[16 + ln15];
  f32x4 mac[2][2];
  #pragma unroll
  for (int et = 0; et < 2; ++et) {
    mac[et][0] = (f32x4){b20, b20, b20, b20};
    mac[et][1] = (f32x4){b21, b21, b21, b21};
  }

  // ---- 8 chunks of 32 h-cols (j-tiles 0..15); B then C per chunk ----
  #pragma unroll 1
  for (int chunk = 0; chunk < 8; ++chunk) {
    #pragma unroll
    for (int jl = 0; jl < 2; ++jl) {
      const int jt = chunk * 2 + jl;
      f32x4 b4 = *(const f32x4*)&B1P[jt * 16 + kg * 4];
      f32x4 w4 = *(const f32x4*)&WRP[jt * 16 + kg * 4];
      short8 a[4];
      #pragma unroll
      for (int ks = 0; ks < 4; ++ks)
        a[ks] = *(const short8*)&W1T[(jt * 16 + ln15) * W1T_K + ks * 32 + kg * 8];
      __builtin_amdgcn_s_setprio(1);
      #pragma unroll
      for (int et = 0; et < 2; ++et) {
        const float dv = et ? distB : distA;
        f32x4 acc;
        #pragma unroll
        for (int r = 0; r < 4; ++r) acc[r] = fmaf(dv, w4[r], b4[r]);
        #pragma unroll
        for (int ks = 0; ks < 4; ++ks)
          acc = __builtin_amdgcn_mfma_f32_16x16x32_bf16(a[ks], einB[et][ks], acc, 0, 0, 0);
        uint2 uu;
        uu.x = cvt_pk(fsilu(acc[0]), fsilu(acc[1]));
        uu.y = cvt_pk(fsilu(acc[2]), fsilu(acc[3]));
        *(uint2*)&hLds[(wid * 32 + et * 16 + ln15) * HSTR2 + jl * 16 + kg * 4] = uu;
      }
      __builtin_amdgcn_s_setprio(0);
    }
    // phase C partial: this chunk's 32 k values
    {
      const int kglob = chunk * 32;
      short8 w0 = *(const short8*)&W2T[ln15 * H1T + kglob + kg * 8];
      short8 w1 = *(const short8*)&W2T[(16 + ln15) * H1T + kglob + kg * 8];
      __builtin_amdgcn_s_setprio(1);
      #pragma unroll
      for (int et = 0; et < 2; ++et) {
        short8 ah = *(const short8*)&hLds[(wid * 32 + et * 16 + ln15) * HSTR2 + kg * 8];
        mac[et][0] = __builtin_amdgcn_mfma_f32_16x16x32_bf16(ah, w0, mac[et][0], 0, 0, 0);
        mac[et][1] = __builtin_amdgcn_mfma_f32_16x16x32_bf16(ah, w1, mac[et][1], 0, 0, 0);
      }
      __builtin_amdgcn_s_setprio(0);
    }
  }
  // ---- epilogue chunk: j-tile 16 (cols 256-271; 256,257 real) + zero pad ----
  {
    const int jt = 16;
    f32x4 b4 = *(const f32x4*)&B1P[jt * 16 + kg * 4];
    f32x4 w4 = *(const f32x4*)&WRP[jt * 16 + kg * 4];
    short8 a[4];
    #pragma unroll
    for (int ks = 0; ks < 4; ++ks)
      a[ks] = *(const short8*)&W1T[(jt * 16 + ln15) * W1T_K + ks * 32 + kg * 8];
    __builtin_amdgcn_s_setprio(1);
    #pragma unroll
    for (int et = 0; et < 2; ++et) {
      const float dv = et ? distB : distA;
      f32x4 acc;
      #pragma unroll
      for (int r = 0; r < 4; ++r) acc[r] = fmaf(dv, w4[r], b4[r]);
      #pragma unroll
      for (int ks = 0; ks < 4; ++ks)
        acc = __builtin_amdgcn_mfma_f32_16x16x32_bf16(a[ks], einB[et][ks], acc, 0, 0, 0);
      uint2 uu;
      uu.x = cvt_pk(fsilu(acc[0]), fsilu(acc[1]));
      uu.y = cvt_pk(fsilu(acc[2]), fsilu(acc[3]));
      *(uint2*)&hLds[(wid * 32 + et * 16 + ln15) * HSTR2 + kg * 4] = uu;
      uint2 zz; zz.x = 0u; zz.y = 0u;
      *(uint2*)&hLds[(wid * 32 + et * 16 + ln15) * HSTR2 + 16 + kg * 4] = zz;
    }
    __builtin_amdgcn_s_setprio(0);
    // phase C: cols 256..287 (>=258 are zeros in W2T / zeroed hLds)
    {
      const int kglob = 256;
      short8 w0 = *(const short8*)&W2T[ln15 * H1T + kglob + kg * 8];
      short8 w1 = *(const short8*)&W2T[(16 + ln15) * H1T + kglob + kg * 8];
      __builtin_amdgcn_s_setprio(1);
      #pragma unroll
      for (int et = 0; et < 2; ++et) {
        short8 ah = *(const short8*)&hLds[(wid * 32 + et * 16 + ln15) * HSTR2 + kg * 8];
        mac[et][0] = __builtin_amdgcn_mfma_f32_16x16x32_bf16(ah, w0, mac[et][0], 0, 0, 0);
        mac[et][1] = __builtin_amdgcn_mfma_f32_16x16x32_bf16(ah, w1, mac[et][1], 0, 0, 0);
      }
      __builtin_amdgcn_s_setprio(0);
    }
  }

  #pragma unroll
  for (int et = 0; et < 2; ++et) {
    #pragma unroll
    for (int r = 0; r < 4; ++r) {
      int eg = wid * 32 + et * 16 + kg * 4 + r;
      ml[eg * MLSTR + ln15] = f2bf(fsilu(mac[et][0][r]));
      ml[eg * MLSTR + 16 + ln15] = f2bf(fsilu(mac[et][1][r]));
    }
  }

  const unsigned short* CW1T = cw1t + layer * CH * MDIM;
  const float* CB1 = cb1 + layer * CH;
  const float* CW2v = cW2 + layer * CH;
  short8 amA = *(const short8*)&ml[(wid * 32 + ln15) * MLSTR + kg * 8];
  short8 amB = *(const short8*)&ml[(wid * 32 + 16 + ln15) * MLSTR + kg * 8];
  float psA[4] = {0.f, 0.f, 0.f, 0.f};
  float psB[4] = {0.f, 0.f, 0.f, 0.f};
  #pragma unroll
  for (int nt = 0; nt < 8; ++nt) {
    float cb = CB1[nt * 16 + ln15];
    float w2v = CW2v[nt * 16 + ln15];
    short8 bc = *(const short8*)&CW1T[(nt * 16 + ln15) * MDIM + kg * 8];
    f32x4 cA = {cb, cb, cb, cb};
    f32x4 cB = {cb, cb, cb, cb};
    __builtin_amdgcn_s_setprio(1);
    cA = __builtin_amdgcn_mfma_f32_16x16x32_bf16(amA, bc, cA, 0, 0, 0);
    cB = __builtin_amdgcn_mfma_f32_16x16x32_bf16(amB, bc, cB, 0, 0, 0);
    __builtin_amdgcn_s_setprio(0);
    #pragma unroll
    for (int r = 0; r < 4; ++r) {
      psA[r] += fsilu(cA[r]) * w2v;
      psB[r] += fsilu(cB[r]) * w2v;
    }
  }
  #pragma unroll
  for (int off = 1; off < 16; off <<= 1) {
    #pragma unroll
    for (int r = 0; r < 4; ++r) {
      psA[r] += __shfl_xor(psA[r], off, 64);
      psB[r] += __shfl_xor(psB[r], off, 64);
    }
  }
  float cwvA = 0.0f, cwvB = 0.0f;
  #pragma unroll
  for (int r = 0; r < 4; ++r) {
    float tA = __shfl(psA[r], ((lane & 15) >> 2) * 16, 64);
    float tB = __shfl(psB[r], ((lane & 15) >> 2) * 16, 64);
    if ((lane & 3) == r) { cwvA = tA; cwvB = tB; }
  }

  #pragma unroll
  for (int it = 0; it < 2; ++it) {
    int idx = lane + it * 64;
    int el = idx >> 2, seg = idx & 3;
    short8 v = *(const short8*)&ml[(wid * 32 + el) * MLSTR + seg * 8];
    *(short8*)&ms[(size_t)(ew0 + el) * MDIM + seg * 8] = v;
  }
  if (lane < 32) {
    const int hi = lane >> 4;
    float cwv = hi ? cwvB : cwvA;
    float dv = hi ? distB : distA;
    float rx = hi ? rxB : rxA, ry = hi ? ryB : ryA, rz = hi ? rzB : rzA;
    float cw = ftanh(cwv + cb2[layer]);
    float fac = cw * cscale[layer] / fmaxf(sqrtf(dv), 1e-8f);
    *(float4*)&mh4[(size_t)(ew0 + lane) * 4] = make_float4(fac * rx, fac * ry, fac * rz, 0.0f);
  }
}

// ---- MFMA node kernel v3 (best-known) ----
__global__ __launch_bounds__(256, 5)
void node_mfma_kernel(const float* __restrict__ Xin,
                      const unsigned short* __restrict__ XbIn,
                      const unsigned short* __restrict__ ms,
                      const float* __restrict__ mh4,
                      const int* __restrict__ csr,
                      const unsigned short* __restrict__ nw1t, const float* __restrict__ nb1,
                      const unsigned short* __restrict__ nw2t, const float* __restrict__ nb2,
                      float* __restrict__ Xout, unsigned short* __restrict__ XbOut,
                      int writeXb, int layer)
{
  __shared__ unsigned short ninLds[64 * NINS];  // 13312 B
  __shared__ unsigned short h1Lds[64 * NH1S];   // 17408 B, reused as f32 out[64][68]
  __shared__ int csrLds[65];
  float* outLds = (float*)h1Lds;

  const int tid = threadIdx.x;
  const int lane = tid & 63;
  const int wid = tid >> 6;
  const int ln15 = lane & 15;
  const int kg = lane >> 4;
  const int n0 = xcd_swz(blockIdx.x, gridDim.x) * 64;

  if (tid < 65) {
    int nn = n0 + tid;
    csrLds[tid] = (nn <= N_NODES) ? csr[nn] : 0;
  }
  #pragma unroll
  for (int it = 0; it < 2; ++it) {
    int idx = tid + it * 256;
    int nl = idx >> 3, c = idx & 7;
    int n = n0 + nl;
    uint4 v = make_uint4(0, 0, 0, 0);
    if (n < N_NODES) v = *(const uint4*)&XbIn[n * 64 + c * 8];
    *(uint4*)&ninLds[nl * NINS + c * 8] = v;
  }
  __syncthreads();

  // gather m_i + mhat: 8 threads/node, 2 passes
  #pragma unroll 1
  for (int pass = 0; pass < 2; ++pass) {
    const int nl = (tid >> 3) + pass * 32;
    const int sub = tid & 7;
    const int colq = sub & 3;
    const int rhalf = sub >> 2;
    const int n = n0 + nl;
    int off = csrLds[nl], end = csrLds[nl + 1];
    if (n >= N_NODES) { off = 0; end = 0; }
    float s0 = 0, s1 = 0, s2 = 0, s3 = 0, s4 = 0, s5 = 0, s6 = 0, s7 = 0;
    for (int r = off + rhalf; r < end; r += 2) {
      uint4 q = *(const uint4*)&ms[(size_t)r * MDIM + colq * 8];
      union { unsigned u; float f; } t;
      t.u = q.x << 16;         s0 += t.f;
      t.u = q.x & 0xFFFF0000u; s1 += t.f;
      t.u = q.y << 16;         s2 += t.f;
      t.u = q.y & 0xFFFF0000u; s3 += t.f;
      t.u = q.z << 16;         s4 += t.f;
      t.u = q.z & 0xFFFF0000u; s5 += t.f;
      t.u = q.w << 16;         s6 += t.f;
      t.u = q.w & 0xFFFF0000u; s7 += t.f;
    }
    s0 += __shfl_xor(s0, 4, 64);
    s1 += __shfl_xor(s1, 4, 64);
    s2 += __shfl_xor(s2, 4, 64);
    s3 += __shfl_xor(s3, 4, 64);
    s4 += __shfl_xor(s4, 4, 64);
    s5 += __shfl_xor(s5, 4, 64);
    s6 += __shfl_xor(s6, 4, 64);
    s7 += __shfl_xor(s7, 4, 64);
    if (rhalf == 0) {
      uint4 mo;
      mo.x = cvt_pk(s0, s1);
      mo.y = cvt_pk(s2, s3);
      mo.z = cvt_pk(s4, s5);
      mo.w = cvt_pk(s6, s7);
      *(uint4*)&ninLds[nl * NINS + FDIM + colq * 8] = mo;
    }
    float mx = 0, my = 0, mz = 0;
    for (int r = off + sub; r < end; r += 8) {
      float4 q = *(const float4*)&mh4[(size_t)r * 4];
      mx += q.x; my += q.y; mz += q.z;
    }
    mx += __shfl_xor(mx, 1, 64); mx += __shfl_xor(mx, 2, 64); mx += __shfl_xor(mx, 4, 64);
    my += __shfl_xor(my, 1, 64); my += __shfl_xor(my, 2, 64); my += __shfl_xor(my, 4, 64);
    mz += __shfl_xor(mz, 1, 64); mz += __shfl_xor(mz, 2, 64); mz += __shfl_xor(mz, 4, 64);
    if (sub == 0 && n < N_NODES) {
      Xout[n * XDIM + 0] = Xin[n * XDIM + 0] + mx;
      Xout[n * XDIM + 1] = Xin[n * XDIM + 1] + my;
      Xout[n * XDIM + 2] = Xin[n * XDIM + 2] + mz;
    }
  }
  __syncthreads();

  // M1: h1T = silu(nW1T . n_inT + nb1)
  const unsigned short* W1 = nw1t + layer * NH * NINS;
  const float* B1 = nb1 + layer * NH;
  for (int jt = wid; jt < 8; jt += 4) {
    f32x4 b4 = *(const f32x4*)&B1[jt * 16 + kg * 4];
    short8 a[3];
    #pragma unroll
    for (int ks = 0; ks < 3; ++ks)
      a[ks] = *(const short8*)&W1[(jt * 16 + ln15) * NINS + ks * 32 + kg * 8];
    #pragma unroll
    for (int et = 0; et < 4; ++et) {
      f32x4 acc = b4;
      #pragma unroll
      for (int ks = 0; ks < 3; ++ks) {
        short8 b = *(const short8*)&ninLds[(et * 16 + ln15) * NINS + ks * 32 + kg * 8];
        acc = __builtin_amdgcn_mfma_f32_16x16x32_bf16(a[ks], b, acc, 0, 0, 0);
      }
      uint2 uu;
      uu.x = cvt_pk(fsilu(acc[0]), fsilu(acc[1]));
      uu.y = cvt_pk(fsilu(acc[2]), fsilu(acc[3]));
      *(uint2*)&h1Lds[(et * 16 + ln15) * NH1S + jt * 16 + kg * 4] = uu;
    }
  }
  __syncthreads();

  // M2: outT = nW2T . h1T + nb2
  const unsigned short* W2 = nw2t + layer * FDIM * NW2K;
  const float* B2 = nb2 + layer * FDIM;
  f32x4 oacc[4];
  {
    int jt = wid;
    f32x4 b4 = *(const f32x4*)&B2[jt * 16 + kg * 4];
    short8 a[4];
    #pragma unroll
    for (int ks = 0; ks < 4; ++ks)
      a[ks] = *(const short8*)&W2[(jt * 16 + ln15) * NW2K + ks * 32 + kg * 8];
    #pragma unroll
    for (int et = 0; et < 4; ++et) {
      f32x4 acc = b4;
      #pragma unroll
      for (int ks = 0; ks < 4; ++ks) {
        short8 b = *(const short8*)&h1Lds[(et * 16 + ln15) * NH1S + ks * 32 + kg * 8];
        acc = __builtin_amdgcn_mfma_f32_16x16x32_bf16(a[ks], b, acc, 0, 0, 0);
      }
      oacc[et] = acc;
    }
  }
  __syncthreads();
  {
    int jt = wid;
    #pragma unroll
    for (int et = 0; et < 4; ++et)
      *(f32x4*)&outLds[(et * 16 + ln15) * 68 + jt * 16 + kg * 4] = oacc[et];
  }
  __syncthreads();

  #pragma unroll
  for (int it = 0; it < 16; ++it) {
    int idx = tid + it * 256;
    int nl = idx >> 6, c = idx & 63;
    int n = n0 + nl;
    if (n < N_NODES) {
      float v = Xin[n * XDIM + PDIM + c] + outLds[nl * 68 + c];
      Xout[n * XDIM + PDIM + c] = v;
      if (writeXb) XbOut[n * 64 + c] = f2bf(v);
    }
  }
}

extern "C" void kernel_launch(void* const* d_in, const int* in_sizes, int n_in,
                              void* d_out, int out_size, void* d_ws, size_t ws_size,
                              hipStream_t stream) {
  const float* x      = (const float*)d_in[0];
  const int*   ei     = (const int*)d_in[1];
  const float* eW1    = (const float*)d_in[2];
  const float* eb1    = (const float*)d_in[3];
  const float* eW2    = (const float*)d_in[4];
  const float* eb2    = (const float*)d_in[5];
  const float* cW1    = (const float*)d_in[6];
  const float* cb1    = (const float*)d_in[7];
  const float* cW2    = (const float*)d_in[8];
  const float* cb2    = (const float*)d_in[9];
  const float* nW1    = (const float*)d_in[10];
  const float* nb1    = (const float*)d_in[11];
  const float* nW2    = (const float*)d_in[12];
  const float* nb2    = (const float*)d_in[13];
  const float* cscale = (const float*)d_in[14];

  float* ws     = (float*)d_ws;
  float* X1     = ws;                                   // N*67 f32
  float* mh4    = X1 + N_NODES * XDIM;                  // E*4 f32
  int*   csr    = (int*)(mh4 + (size_t)N_EDGES * 4);    // N+4
  int*   cursor = csr + N_NODES + 4;                    // N
  int*   cnt    = cursor + N_NODES;                     // N
  int*   srcS   = cnt + N_NODES;                        // E
  int*   dstS   = srcS + N_EDGES;                       // E
  unsigned short* w1t  = (unsigned short*)(dstS + N_EDGES);
  unsigned short* w2t  = w1t + NLAYERS * H1T * W1T_K;
  unsigned short* cw1t = w2t + NLAYERS * MDIM * H1T;
  unsigned short* nw1t = cw1t + NLAYERS * CH * MDIM;
  unsigned short* nw2t = nw1t + NLAYERS * NH * NINS;
  float* b1p = (float*)(nw2t + NLAYERS * FDIM * NW2K);
  float* wrp = b1p + NLAYERS * H1T;
  unsigned short* Xb = (unsigned short*)(wrp + NLAYERS * H1T);  // N*64 bf16
  unsigned short* ms = Xb + (size_t)N_NODES * 64;               // E*32 bf16

  hipMemsetAsync(cnt, 0, N_NODES * sizeof(int), stream);
  setup_kernel<<<COUNT_BLOCKS + PREP_BLOCKS + CONV_BLOCKS, 256, 0, stream>>>(
      ei, cnt, eW1, eW2, cW1, eb1, nW1, nW2,
      w1t, w2t, cw1t, nw1t, nw2t, b1p, wrp, x, Xb);
  scan_kernel<<<1, 1024, 0, stream>>>(cnt, csr, cursor);
  rank_kernel<<<(N_EDGES + 255) / 256, 256, 0, stream>>>(ei, cursor, srcS, dstS);

  const int nodeBlocks = (N_NODES + 63) / 64;
  for (int l = 0; l < NLAYERS; ++l) {
    const float* Xin = (l == 0) ? x : X1;
    float* Xout = (l == 0) ? X1 : (float*)d_out;
    edge_mfma_kernel<<<N_EDGES / 128, 256, 0, stream>>>(
        Xin, Xb, srcS, dstS, w1t, b1p, wrp, w2t, eb2, cw1t, cb1, cW2, cb2, cscale,
        ms, mh4, l);
    node_mfma_kernel<<<nodeBlocks, 256, 0, stream>>>(
        Xin, Xb, ms, mh4, csr, nw1t, nb1, nw2t, nb2, Xout, Xb, (l == 0) ? 1 : 0, l);
  }
}

// Round 20
// 633.008 us; speedup vs baseline: 1.1248x; 1.0033x over previous
//
#include <hip/hip_runtime.h>

#define N_NODES 50000
#define N_EDGES 800000
#define PDIM 3
#define FDIM 64
#define MDIM 32
#define NLAYERS 2
#define EINDIM 129
#define H1 258
#define CH 128
#define NH 128
#define XDIM 67
#define H1T 288
#define HSTR2 40        // hLds col stride (bf16): 80B = 5 quanta (odd -> conflict-free b128)
#define W1T_K 136
#define MLSTR 40
#define NINS 104
#define NH1S 136
#define NW2K 128

typedef __attribute__((ext_vector_type(8))) short short8;
typedef __attribute__((ext_vector_type(4))) float f32x4;

#define LOG2E 1.4426950408889634f

__device__ __forceinline__ float fsilu(float x) {
  float e = __builtin_amdgcn_exp2f(-x * LOG2E);
  return x * __builtin_amdgcn_rcpf(1.0f + e);
}

__device__ __forceinline__ float ftanh(float x) {
  float xc = fminf(fmaxf(x, -15.0f), 15.0f);
  float E = __builtin_amdgcn_exp2f(2.0f * LOG2E * xc);
  return (E - 1.0f) * __builtin_amdgcn_rcpf(E + 1.0f);
}

__device__ __forceinline__ unsigned short f2bf(float f) {
  union { float f; unsigned u; } v; v.f = f;
  unsigned r = v.u + 0x7FFF + ((v.u >> 16) & 1);  // RNE
  return (unsigned short)(r >> 16);
}

__device__ __forceinline__ unsigned cvt_pk(float lo, float hi) {
  unsigned r;
  asm("v_cvt_pk_bf16_f32 %0, %1, %2" : "=v"(r) : "v"(lo), "v"(hi));
  return r;
}

// bijective XCD-chunk swizzle (m204)
__device__ __forceinline__ int xcd_swz(int bid, int nwg) {
  const int nx = 8;
  int q = nwg / nx, r = nwg % nx;
  int xcd = bid % nx, idx = bid / nx;
  return (xcd < r) ? xcd * (q + 1) + idx : r * (q + 1) + (xcd - r) * q + idx;
}

#define COUNT_BLOCKS 3125   // 800000/256
#define PREP_TOTAL (NLAYERS * (H1T * W1T_K + MDIM * H1T + CH * MDIM + 2 * H1T \
                               + NH * NINS + FDIM * NW2K))
#define PREP_BLOCKS ((PREP_TOTAL + 255) / 256)
#define CONV_BLOCKS ((N_NODES * 8 + 255) / 256)

// fused setup: count histogram + weight prep + X bf16 conversion
__global__ void setup_kernel(const int* __restrict__ ei, int* __restrict__ cnt,
                             const float* __restrict__ eW1, const float* __restrict__ eW2,
                             const float* __restrict__ cW1, const float* __restrict__ eb1,
                             const float* __restrict__ nW1, const float* __restrict__ nW2,
                             unsigned short* __restrict__ w1t, unsigned short* __restrict__ w2t,
                             unsigned short* __restrict__ cw1t,
                             unsigned short* __restrict__ nw1t, unsigned short* __restrict__ nw2t,
                             float* __restrict__ b1p, float* __restrict__ wrp,
                             const float* __restrict__ X, unsigned short* __restrict__ Xb) {
  const int bid = blockIdx.x;
  const int tid = threadIdx.x;
  if (bid < COUNT_BLOCKS) {
    int e = bid * 256 + tid;
    if (e < N_EDGES) atomicAdd(&cnt[ei[N_EDGES + e]], 1);
    return;
  }
  if (bid < COUNT_BLOCKS + PREP_BLOCKS) {
    int idx = (bid - COUNT_BLOCKS) * 256 + tid;
    const int n1 = NLAYERS * H1T * W1T_K;
    const int n2 = NLAYERS * MDIM * H1T;
    const int n3 = NLAYERS * CH * MDIM;
    const int n4 = NLAYERS * H1T;
    const int n5 = NLAYERS * NH * NINS;
    const int n6 = NLAYERS * FDIM * NW2K;
    if (idx < n1) {
      int k = idx % W1T_K;
      int rest = idx / W1T_K;
      int j = rest % H1T;
      int l = rest / H1T;
      float v = (k < 128 && j < H1) ? eW1[(l * EINDIM + k) * H1 + j] : 0.0f;
      w1t[idx] = f2bf(v);
    } else if (idx < n1 + n2) {
      int t = idx - n1;
      int k = t % H1T;
      int rest = t / H1T;
      int n = rest % MDIM;
      int l = rest / MDIM;
      float v = (k < H1) ? eW2[(l * H1 + k) * MDIM + n] : 0.0f;
      w2t[t] = f2bf(v);
    } else if (idx < n1 + n2 + n3) {
      int t = idx - n1 - n2;
      int k = t % MDIM;
      int rest = t / MDIM;
      int n = rest % CH;
      int l = rest / CH;
      cw1t[t] = f2bf(cW1[(l * MDIM + k) * CH + n]);
    } else if (idx < n1 + n2 + n3 + n4) {
      int t = idx - n1 - n2 - n3;
      int j = t % H1T;
      int l = t / H1T;
      b1p[t] = (j < H1) ? eb1[l * H1 + j] : 0.0f;
    } else if (idx < n1 + n2 + n3 + 2 * n4) {
      int t = idx - n1 - n2 - n3 - n4;
      int j = t % H1T;
      int l = t / H1T;
      wrp[t] = (j < H1) ? eW1[((size_t)l * EINDIM + 128) * H1 + j] : 0.0f;
    } else if (idx < n1 + n2 + n3 + 2 * n4 + n5) {
      int t = idx - n1 - n2 - n3 - 2 * n4;
      int k = t % NINS;
      int rest = t / NINS;
      int j = rest % NH;
      int l = rest / NH;
      float v = (k < FDIM + MDIM) ? nW1[(l * (FDIM + MDIM) + k) * NH + j] : 0.0f;
      nw1t[t] = f2bf(v);
    } else if (idx < n1 + n2 + n3 + 2 * n4 + n5 + n6) {
      int t = idx - n1 - n2 - n3 - 2 * n4 - n5;
      int k = t % NW2K;
      int rest = t / NW2K;
      int j = rest % FDIM;
      int l = rest / FDIM;
      nw2t[t] = f2bf(nW2[(l * NH + k) * FDIM + j]);
    }
    return;
  }
  {
    int idx = (bid - COUNT_BLOCKS - PREP_BLOCKS) * 256 + tid;
    if (idx >= N_NODES * 8) return;
    int n = idx >> 3, c = idx & 7;
    const float* src = X + n * XDIM + PDIM + c * 8;
    short8 v;
    #pragma unroll
    for (int i = 0; i < 8; ++i) v[i] = (short)f2bf(src[i]);
    *(short8*)&Xb[n * 64 + c * 8] = v;
  }
}

__global__ __launch_bounds__(1024)
void scan_kernel(const int* __restrict__ cnt, int* __restrict__ csr, int* __restrict__ cursor) {
  __shared__ int partial[1024];
  const int tid = threadIdx.x;
  const int CHUNK = 49;
  int base = tid * CHUNK;
  int s = 0;
  for (int i = 0; i < CHUNK; ++i) {
    int idx = base + i;
    if (idx < N_NODES) s += cnt[idx];
  }
  partial[tid] = s;
  __syncthreads();
  for (int off = 1; off < 1024; off <<= 1) {
    int v = (tid >= off) ? partial[tid - off] : 0;
    __syncthreads();
    partial[tid] += v;
    __syncthreads();
  }
  int run = partial[tid] - s;
  for (int i = 0; i < CHUNK; ++i) {
    int idx = base + i;
    if (idx < N_NODES) {
      csr[idx] = run;
      cursor[idx] = run;
      run += cnt[idx];
    }
  }
  if (tid == 1023) csr[N_NODES] = run;
}

__global__ void rank_kernel(const int* __restrict__ ei, int* __restrict__ cursor,
                            int* __restrict__ srcS, int* __restrict__ dstS) {
  int e = blockIdx.x * 256 + threadIdx.x;
  if (e < N_EDGES) {
    int s = ei[e];
    int d = ei[N_EDGES + e];
    int p = atomicAdd(&cursor[d], 1);
    srcS[p] = s;
    dstS[p] = d;
  }
}

// Edge kernel v9: R19 (17-tile + setprio) with the chunk loop unrolled 2x so
// chunk k+1's W1T global loads can issue under chunk k's phase-C MFMA chain.
__global__ __launch_bounds__(256, 4)
void edge_mfma_kernel(const float* __restrict__ X,
                      const unsigned short* __restrict__ Xb,
                      const int* __restrict__ srcS, const int* __restrict__ dstS,
                      const unsigned short* __restrict__ w1t,
                      const float* __restrict__ b1p, const float* __restrict__ wrp,
                      const unsigned short* __restrict__ w2t, const float* __restrict__ eb2,
                      const unsigned short* __restrict__ cw1t, const float* __restrict__ cb1,
                      const float* __restrict__ cW2, const float* __restrict__ cb2,
                      const float* __restrict__ cscale,
                      unsigned short* __restrict__ ms, float* __restrict__ mh4,
                      int layer)
{
  __shared__ unsigned short hLds[128 * HSTR2];  // 10240 B, wave-partitioned rows
  __shared__ unsigned short ml[128 * MLSTR];    // 10240 B

  const int tid = threadIdx.x;
  const int lane = tid & 63;
  const int wid = tid >> 6;
  const int ln15 = lane & 15;
  const int kg = lane >> 4;
  const int e0 = xcd_swz(blockIdx.x, gridDim.x) * 128;
  const int ew0 = e0 + wid * 32;

  const int eA = ew0 + ln15;
  const int eB = ew0 + 16 + ln15;
  const int sA = srcS[eA], dA = dstS[eA];
  const int sB = srcS[eB], dB = dstS[eB];
  float rxA = X[sA * XDIM + 0] - X[dA * XDIM + 0];
  float ryA = X[sA * XDIM + 1] - X[dA * XDIM + 1];
  float rzA = X[sA * XDIM + 2] - X[dA * XDIM + 2];
  float rxB = X[sB * XDIM + 0] - X[dB * XDIM + 0];
  float ryB = X[sB * XDIM + 1] - X[dB * XDIM + 1];
  float rzB = X[sB * XDIM + 2] - X[dB * XDIM + 2];
  const float distA = rxA * rxA + ryA * ryA + rzA * rzA;
  const float distB = rxB * rxB + ryB * ryB + rzB * rzB;

  short8 einB[2][4];
  #pragma unroll
  for (int ks = 0; ks < 4; ++ks) {
    int nA = (ks < 2) ? dA : sA;
    int nB = (ks < 2) ? dB : sB;
    einB[0][ks] = *(const short8*)&Xb[nA * 64 + (ks & 1) * 32 + kg * 8];
    einB[1][ks] = *(const short8*)&Xb[nB * 64 + (ks & 1) * 32 + kg * 8];
  }

  const unsigned short* W1T = w1t + layer * H1T * W1T_K;
  const float* B1P = b1p + layer * H1T;
  const float* WRP = wrp + layer * H1T;
  const unsigned short* W2T = w2t + layer * MDIM * H1T;
  const float* B2 = eb2 + layer * MDIM;

  float b20 = B2[ln15], b21 = B2[16 + ln15];
  f32x4 mac[2][2];
  #pragma unroll
  for (int et = 0; et < 2; ++et) {
    mac[et][0] = (f32x4){b20, b20, b20, b20};
    mac[et][1] = (f32x4){b21, b21, b21, b21};
  }

  // ---- 8 chunks of 32 h-cols (j-tiles 0..15); unroll 2 for cross-chunk
  //      load/compute overlap ----
  #pragma unroll 2
  for (int chunk = 0; chunk < 8; ++chunk) {
    #pragma unroll
    for (int jl = 0; jl < 2; ++jl) {
      const int jt = chunk * 2 + jl;
      f32x4 b4 = *(const f32x4*)&B1P[jt * 16 + kg * 4];
      f32x4 w4 = *(const f32x4*)&WRP[jt * 16 + kg * 4];
      short8 a[4];
      #pragma unroll
      for (int ks = 0; ks < 4; ++ks)
        a[ks] = *(const short8*)&W1T[(jt * 16 + ln15) * W1T_K + ks * 32 + kg * 8];
      __builtin_amdgcn_s_setprio(1);
      #pragma unroll
      for (int et = 0; et < 2; ++et) {
        const float dv = et ? distB : distA;
        f32x4 acc;
        #pragma unroll
        for (int r = 0; r < 4; ++r) acc[r] = fmaf(dv, w4[r], b4[r]);
        #pragma unroll
        for (int ks = 0; ks < 4; ++ks)
          acc = __builtin_amdgcn_mfma_f32_16x16x32_bf16(a[ks], einB[et][ks], acc, 0, 0, 0);
        uint2 uu;
        uu.x = cvt_pk(fsilu(acc[0]), fsilu(acc[1]));
        uu.y = cvt_pk(fsilu(acc[2]), fsilu(acc[3]));
        *(uint2*)&hLds[(wid * 32 + et * 16 + ln15) * HSTR2 + jl * 16 + kg * 4] = uu;
      }
      __builtin_amdgcn_s_setprio(0);
    }
    // phase C partial: this chunk's 32 k values
    {
      const int kglob = chunk * 32;
      short8 w0 = *(const short8*)&W2T[ln15 * H1T + kglob + kg * 8];
      short8 w1 = *(const short8*)&W2T[(16 + ln15) * H1T + kglob + kg * 8];
      __builtin_amdgcn_s_setprio(1);
      #pragma unroll
      for (int et = 0; et < 2; ++et) {
        short8 ah = *(const short8*)&hLds[(wid * 32 + et * 16 + ln15) * HSTR2 + kg * 8];
        mac[et][0] = __builtin_amdgcn_mfma_f32_16x16x32_bf16(ah, w0, mac[et][0], 0, 0, 0);
        mac[et][1] = __builtin_amdgcn_mfma_f32_16x16x32_bf16(ah, w1, mac[et][1], 0, 0, 0);
      }
      __builtin_amdgcn_s_setprio(0);
    }
  }
  // ---- epilogue chunk: j-tile 16 (cols 256-271; 256,257 real) + zero pad ----
  {
    const int jt = 16;
    f32x4 b4 = *(const f32x4*)&B1P[jt * 16 + kg * 4];
    f32x4 w4 = *(const f32x4*)&WRP[jt * 16 + kg * 4];
    short8 a[4];
    #pragma unroll
    for (int ks = 0; ks < 4; ++ks)
      a[ks] = *(const short8*)&W1T[(jt * 16 + ln15) * W1T_K + ks * 32 + kg * 8];
    __builtin_amdgcn_s_setprio(1);
    #pragma unroll
    for (int et = 0; et < 2; ++et) {
      const float dv = et ? distB : distA;
      f32x4 acc;
      #pragma unroll
      for (int r = 0; r < 4; ++r) acc[r] = fmaf(dv, w4[r], b4[r]);
      #pragma unroll
      for (int ks = 0; ks < 4; ++ks)
        acc = __builtin_amdgcn_mfma_f32_16x16x32_bf16(a[ks], einB[et][ks], acc, 0, 0, 0);
      uint2 uu;
      uu.x = cvt_pk(fsilu(acc[0]), fsilu(acc[1]));
      uu.y = cvt_pk(fsilu(acc[2]), fsilu(acc[3]));
      *(uint2*)&hLds[(wid * 32 + et * 16 + ln15) * HSTR2 + kg * 4] = uu;
      uint2 zz; zz.x = 0u; zz.y = 0u;
      *(uint2*)&hLds[(wid * 32 + et * 16 + ln15) * HSTR2 + 16 + kg * 4] = zz;
    }
    __builtin_amdgcn_s_setprio(0);
    // phase C: cols 256..287 (>=258 are zeros in W2T / zeroed hLds)
    {
      const int kglob = 256;
      short8 w0 = *(const short8*)&W2T[ln15 * H1T + kglob + kg * 8];
      short8 w1 = *(const short8*)&W2T[(16 + ln15) * H1T + kglob + kg * 8];
      __builtin_amdgcn_s_setprio(1);
      #pragma unroll
      for (int et = 0; et < 2; ++et) {
        short8 ah = *(const short8*)&hLds[(wid * 32 + et * 16 + ln15) * HSTR2 + kg * 8];
        mac[et][0] = __builtin_amdgcn_mfma_f32_16x16x32_bf16(ah, w0, mac[et][0], 0, 0, 0);
        mac[et][1] = __builtin_amdgcn_mfma_f32_16x16x32_bf16(ah, w1, mac[et][1], 0, 0, 0);
      }
      __builtin_amdgcn_s_setprio(0);
    }
  }

  #pragma unroll
  for (int et = 0; et < 2; ++et) {
    #pragma unroll
    for (int r = 0; r < 4; ++r) {
      int eg = wid * 32 + et * 16 + kg * 4 + r;
      ml[eg * MLSTR + ln15] = f2bf(fsilu(mac[et][0][r]));
      ml[eg * MLSTR + 16 + ln15] = f2bf(fsilu(mac[et][1][r]));
    }
  }

  const unsigned short* CW1T = cw1t + layer * CH * MDIM;
  const float* CB1 = cb1 + layer * CH;
  const float* CW2v = cW2 + layer * CH;
  short8 amA = *(const short8*)&ml[(wid * 32 + ln15) * MLSTR + kg * 8];
  short8 amB = *(const short8*)&ml[(wid * 32 + 16 + ln15) * MLSTR + kg * 8];
  float psA[4] = {0.f, 0.f, 0.f, 0.f};
  float psB[4] = {0.f, 0.f, 0.f, 0.f};
  #pragma unroll
  for (int nt = 0; nt < 8; ++nt) {
    float cb = CB1[nt * 16 + ln15];
    float w2v = CW2v[nt * 16 + ln15];
    short8 bc = *(const short8*)&CW1T[(nt * 16 + ln15) * MDIM + kg * 8];
    f32x4 cA = {cb, cb, cb, cb};
    f32x4 cB = {cb, cb, cb, cb};
    __builtin_amdgcn_s_setprio(1);
    cA = __builtin_amdgcn_mfma_f32_16x16x32_bf16(amA, bc, cA, 0, 0, 0);
    cB = __builtin_amdgcn_mfma_f32_16x16x32_bf16(amB, bc, cB, 0, 0, 0);
    __builtin_amdgcn_s_setprio(0);
    #pragma unroll
    for (int r = 0; r < 4; ++r) {
      psA[r] += fsilu(cA[r]) * w2v;
      psB[r] += fsilu(cB[r]) * w2v;
    }
  }
  #pragma unroll
  for (int off = 1; off < 16; off <<= 1) {
    #pragma unroll
    for (int r = 0; r < 4; ++r) {
      psA[r] += __shfl_xor(psA[r], off, 64);
      psB[r] += __shfl_xor(psB[r], off, 64);
    }
  }
  float cwvA = 0.0f, cwvB = 0.0f;
  #pragma unroll
  for (int r = 0; r < 4; ++r) {
    float tA = __shfl(psA[r], ((lane & 15) >> 2) * 16, 64);
    float tB = __shfl(psB[r], ((lane & 15) >> 2) * 16, 64);
    if ((lane & 3) == r) { cwvA = tA; cwvB = tB; }
  }

  #pragma unroll
  for (int it = 0; it < 2; ++it) {
    int idx = lane + it * 64;
    int el = idx >> 2, seg = idx & 3;
    short8 v = *(const short8*)&ml[(wid * 32 + el) * MLSTR + seg * 8];
    *(short8*)&ms[(size_t)(ew0 + el) * MDIM + seg * 8] = v;
  }
  if (lane < 32) {
    const int hi = lane >> 4;
    float cwv = hi ? cwvB : cwvA;
    float dv = hi ? distB : distA;
    float rx = hi ? rxB : rxA, ry = hi ? ryB : ryA, rz = hi ? rzB : rzA;
    float cw = ftanh(cwv + cb2[layer]);
    float fac = cw * cscale[layer] / fmaxf(sqrtf(dv), 1e-8f);
    *(float4*)&mh4[(size_t)(ew0 + lane) * 4] = make_float4(fac * rx, fac * ry, fac * rz, 0.0f);
  }
}

// ---- MFMA node kernel v3 (best-known) ----
__global__ __launch_bounds__(256, 5)
void node_mfma_kernel(const float* __restrict__ Xin,
                      const unsigned short* __restrict__ XbIn,
                      const unsigned short* __restrict__ ms,
                      const float* __restrict__ mh4,
                      const int* __restrict__ csr,
                      const unsigned short* __restrict__ nw1t, const float* __restrict__ nb1,
                      const unsigned short* __restrict__ nw2t, const float* __restrict__ nb2,
                      float* __restrict__ Xout, unsigned short* __restrict__ XbOut,
                      int writeXb, int layer)
{
  __shared__ unsigned short ninLds[64 * NINS];  // 13312 B
  __shared__ unsigned short h1Lds[64 * NH1S];   // 17408 B, reused as f32 out[64][68]
  __shared__ int csrLds[65];
  float* outLds = (float*)h1Lds;

  const int tid = threadIdx.x;
  const int lane = tid & 63;
  const int wid = tid >> 6;
  const int ln15 = lane & 15;
  const int kg = lane >> 4;
  const int n0 = xcd_swz(blockIdx.x, gridDim.x) * 64;

  if (tid < 65) {
    int nn = n0 + tid;
    csrLds[tid] = (nn <= N_NODES) ? csr[nn] : 0;
  }
  #pragma unroll
  for (int it = 0; it < 2; ++it) {
    int idx = tid + it * 256;
    int nl = idx >> 3, c = idx & 7;
    int n = n0 + nl;
    uint4 v = make_uint4(0, 0, 0, 0);
    if (n < N_NODES) v = *(const uint4*)&XbIn[n * 64 + c * 8];
    *(uint4*)&ninLds[nl * NINS + c * 8] = v;
  }
  __syncthreads();

  // gather m_i + mhat: 8 threads/node, 2 passes
  #pragma unroll 1
  for (int pass = 0; pass < 2; ++pass) {
    const int nl = (tid >> 3) + pass * 32;
    const int sub = tid & 7;
    const int colq = sub & 3;
    const int rhalf = sub >> 2;
    const int n = n0 + nl;
    int off = csrLds[nl], end = csrLds[nl + 1];
    if (n >= N_NODES) { off = 0; end = 0; }
    float s0 = 0, s1 = 0, s2 = 0, s3 = 0, s4 = 0, s5 = 0, s6 = 0, s7 = 0;
    for (int r = off + rhalf; r < end; r += 2) {
      uint4 q = *(const uint4*)&ms[(size_t)r * MDIM + colq * 8];
      union { unsigned u; float f; } t;
      t.u = q.x << 16;         s0 += t.f;
      t.u = q.x & 0xFFFF0000u; s1 += t.f;
      t.u = q.y << 16;         s2 += t.f;
      t.u = q.y & 0xFFFF0000u; s3 += t.f;
      t.u = q.z << 16;         s4 += t.f;
      t.u = q.z & 0xFFFF0000u; s5 += t.f;
      t.u = q.w << 16;         s6 += t.f;
      t.u = q.w & 0xFFFF0000u; s7 += t.f;
    }
    s0 += __shfl_xor(s0, 4, 64);
    s1 += __shfl_xor(s1, 4, 64);
    s2 += __shfl_xor(s2, 4, 64);
    s3 += __shfl_xor(s3, 4, 64);
    s4 += __shfl_xor(s4, 4, 64);
    s5 += __shfl_xor(s5, 4, 64);
    s6 += __shfl_xor(s6, 4, 64);
    s7 += __shfl_xor(s7, 4, 64);
    if (rhalf == 0) {
      uint4 mo;
      mo.x = cvt_pk(s0, s1);
      mo.y = cvt_pk(s2, s3);
      mo.z = cvt_pk(s4, s5);
      mo.w = cvt_pk(s6, s7);
      *(uint4*)&ninLds[nl * NINS + FDIM + colq * 8] = mo;
    }
    float mx = 0, my = 0, mz = 0;
    for (int r = off + sub; r < end; r += 8) {
      float4 q = *(const float4*)&mh4[(size_t)r * 4];
      mx += q.x; my += q.y; mz += q.z;
    }
    mx += __shfl_xor(mx, 1, 64); mx += __shfl_xor(mx, 2, 64); mx += __shfl_xor(mx, 4, 64);
    my += __shfl_xor(my, 1, 64); my += __shfl_xor(my, 2, 64); my += __shfl_xor(my, 4, 64);
    mz += __shfl_xor(mz, 1, 64); mz += __shfl_xor(mz, 2, 64); mz += __shfl_xor(mz, 4, 64);
    if (sub == 0 && n < N_NODES) {
      Xout[n * XDIM + 0] = Xin[n * XDIM + 0] + mx;
      Xout[n * XDIM + 1] = Xin[n * XDIM + 1] + my;
      Xout[n * XDIM + 2] = Xin[n * XDIM + 2] + mz;
    }
  }
  __syncthreads();

  // M1: h1T = silu(nW1T . n_inT + nb1)
  const unsigned short* W1 = nw1t + layer * NH * NINS;
  const float* B1 = nb1 + layer * NH;
  for (int jt = wid; jt < 8; jt += 4) {
    f32x4 b4 = *(const f32x4*)&B1[jt * 16 + kg * 4];
    short8 a[3];
    #pragma unroll
    for (int ks = 0; ks < 3; ++ks)
      a[ks] = *(const short8*)&W1[(jt * 16 + ln15) * NINS + ks * 32 + kg * 8];
    #pragma unroll
    for (int et = 0; et < 4; ++et) {
      f32x4 acc = b4;
      #pragma unroll
      for (int ks = 0; ks < 3; ++ks) {
        short8 b = *(const short8*)&ninLds[(et * 16 + ln15) * NINS + ks * 32 + kg * 8];
        acc = __builtin_amdgcn_mfma_f32_16x16x32_bf16(a[ks], b, acc, 0, 0, 0);
      }
      uint2 uu;
      uu.x = cvt_pk(fsilu(acc[0]), fsilu(acc[1]));
      uu.y = cvt_pk(fsilu(acc[2]), fsilu(acc[3]));
      *(uint2*)&h1Lds[(et * 16 + ln15) * NH1S + jt * 16 + kg * 4] = uu;
    }
  }
  __syncthreads();

  // M2: outT = nW2T . h1T + nb2
  const unsigned short* W2 = nw2t + layer * FDIM * NW2K;
  const float* B2 = nb2 + layer * FDIM;
  f32x4 oacc[4];
  {
    int jt = wid;
    f32x4 b4 = *(const f32x4*)&B2[jt * 16 + kg * 4];
    short8 a[4];
    #pragma unroll
    for (int ks = 0; ks < 4; ++ks)
      a[ks] = *(const short8*)&W2[(jt * 16 + ln15) * NW2K + ks * 32 + kg * 8];
    #pragma unroll
    for (int et = 0; et < 4; ++et) {
      f32x4 acc = b4;
      #pragma unroll
      for (int ks = 0; ks < 4; ++ks) {
        short8 b = *(const short8*)&h1Lds[(et * 16 + ln15) * NH1S + ks * 32 + kg * 8];
        acc = __builtin_amdgcn_mfma_f32_16x16x32_bf16(a[ks], b, acc, 0, 0, 0);
      }
      oacc[et] = acc;
    }
  }
  __syncthreads();
  {
    int jt = wid;
    #pragma unroll
    for (int et = 0; et < 4; ++et)
      *(f32x4*)&outLds[(et * 16 + ln15) * 68 + jt * 16 + kg * 4] = oacc[et];
  }
  __syncthreads();

  #pragma unroll
  for (int it = 0; it < 16; ++it) {
    int idx = tid + it * 256;
    int nl = idx >> 6, c = idx & 63;
    int n = n0 + nl;
    if (n < N_NODES) {
      float v = Xin[n * XDIM + PDIM + c] + outLds[nl * 68 + c];
      Xout[n * XDIM + PDIM + c] = v;
      if (writeXb) XbOut[n * 64 + c] = f2bf(v);
    }
  }
}

extern "C" void kernel_launch(void* const* d_in, const int* in_sizes, int n_in,
                              void* d_out, int out_size, void* d_ws, size_t ws_size,
                              hipStream_t stream) {
  const float* x      = (const float*)d_in[0];
  const int*   ei     = (const int*)d_in[1];
  const float* eW1    = (const float*)d_in[2];
  const float* eb1    = (const float*)d_in[3];
  const float* eW2    = (const float*)d_in[4];
  const float* eb2    = (const float*)d_in[5];
  const float* cW1    = (const float*)d_in[6];
  const float* cb1    = (const float*)d_in[7];
  const float* cW2    = (const float*)d_in[8];
  const float* cb2    = (const float*)d_in[9];
  const float* nW1    = (const float*)d_in[10];
  const float* nb1    = (const float*)d_in[11];
  const float* nW2    = (const float*)d_in[12];
  const float* nb2    = (const float*)d_in[13];
  const float* cscale = (const float*)d_in[14];

  float* ws     = (float*)d_ws;
  float* X1     = ws;                                   // N*67 f32
  float* mh4    = X1 + N_NODES * XDIM;                  // E*4 f32
  int*   csr    = (int*)(mh4 + (size_t)N_EDGES * 4);    // N+4
  int*   cursor = csr + N_NODES + 4;                    // N
  int*   cnt    = cursor + N_NODES;                     // N
  int*   srcS   = cnt + N_NODES;                        // E
  int*   dstS   = srcS + N_EDGES;                       // E
  unsigned short* w1t  = (unsigned short*)(dstS + N_EDGES);
  unsigned short* w2t  = w1t + NLAYERS * H1T * W1T_K;
  unsigned short* cw1t = w2t + NLAYERS * MDIM * H1T;
  unsigned short* nw1t = cw1t + NLAYERS * CH * MDIM;
  unsigned short* nw2t = nw1t + NLAYERS * NH * NINS;
  float* b1p = (float*)(nw2t + NLAYERS * FDIM * NW2K);
  float* wrp = b1p + NLAYERS * H1T;
  unsigned short* Xb = (unsigned short*)(wrp + NLAYERS * H1T);  // N*64 bf16
  unsigned short* ms = Xb + (size_t)N_NODES * 64;               // E*32 bf16

  hipMemsetAsync(cnt, 0, N_NODES * sizeof(int), stream);
  setup_kernel<<<COUNT_BLOCKS + PREP_BLOCKS + CONV_BLOCKS, 256, 0, stream>>>(
      ei, cnt, eW1, eW2, cW1, eb1, nW1, nW2,
      w1t, w2t, cw1t, nw1t, nw2t, b1p, wrp, x, Xb);
  scan_kernel<<<1, 1024, 0, stream>>>(cnt, csr, cursor);
  rank_kernel<<<(N_EDGES + 255) / 256, 256, 0, stream>>>(ei, cursor, srcS, dstS);

  const int nodeBlocks = (N_NODES + 63) / 64;
  for (int l = 0; l < NLAYERS; ++l) {
    const float* Xin = (l == 0) ? x : X1;
    float* Xout = (l == 0) ? X1 : (float*)d_out;
    edge_mfma_kernel<<<N_EDGES / 128, 256, 0, stream>>>(
        Xin, Xb, srcS, dstS, w1t, b1p, wrp, w2t, eb2, cw1t, cb1, cW2, cb2, cscale,
        ms, mh4, l);
    node_mfma_kernel<<<nodeBlocks, 256, 0, stream>>>(
        Xin, Xb, ms, mh4, csr, nw1t, nb1, nw2t, nb2, Xout, Xb, (l == 0) ? 1 : 0, l);
  }
}